// Round 8
// baseline (731.781 us; speedup 1.0000x reference)
//
#include <hip/hip_runtime.h>
#include <hip/hip_bf16.h>
#include <math.h>

#define H_ 8
#define K_ 128
#define C_ 64
#define D_ 1024
#define T_ 4096
#define B_ 4
#define N_CH 64           // T_/C_
#define BT_ (B_*T_)

typedef __attribute__((ext_vector_type(8))) short bf16x8;
typedef __attribute__((ext_vector_type(4))) float f32x4;
typedef __hip_bfloat16 bf16;

// raw barrier: order LDS (lgkm) only; leave global loads/stores in flight (T4)
#define BAR_LGKM() do { \
  asm volatile("s_waitcnt lgkmcnt(0)" ::: "memory"); \
  __builtin_amdgcn_sched_barrier(0); \
  __builtin_amdgcn_s_barrier(); \
} while(0)

__device__ __forceinline__ float siluf(float x){ return x / (1.0f + expf(-x)); }
__device__ __forceinline__ float expn(float x){ return expf(fminf(x, 0.f)); }
__device__ __forceinline__ float sanf(float v){ return (__builtin_fabsf(v) <= 1e30f) ? v : 0.f; }

__device__ __forceinline__ void ld_bf4(const bf16* p, float* o){
  uint2 u = *(const uint2*)p;
  o[0]=__uint_as_float(u.x<<16); o[1]=__uint_as_float(u.x&0xffff0000u);
  o[2]=__uint_as_float(u.y<<16); o[3]=__uint_as_float(u.y&0xffff0000u);
}
__device__ __forceinline__ void ld_bf4s(const bf16* p, float* o){
  ld_bf4(p, o);
#pragma unroll
  for (int e=0;e<4;e++) o[e] = sanf(o[e]);
}
__device__ __forceinline__ unsigned short f2bfu(float f){
  bf16 h = __float2bfloat16(f);
  return *reinterpret_cast<unsigned short*>(&h);
}
__device__ __forceinline__ uint2 pack_bf4(const float* v){
  uint2 r;
  r.x = (unsigned)f2bfu(v[0]) | ((unsigned)f2bfu(v[1])<<16);
  r.y = (unsigned)f2bfu(v[2]) | ((unsigned)f2bfu(v[3])<<16);
  return r;
}
__device__ __forceinline__ bf16x8 u4_to_b8(uint4 u){
  union { uint4 u; bf16x8 b; } cv; cv.u = u; return cv.b;
}

// ---- fully-unrolled forward substitution (template-const indices: rule #20) ----
template<int I> __device__ __forceinline__ void fsub_step(float* v, const float (*sa)[64]){
  const float* ar = sa[I];
  float s0=0.f,s1=0.f,s2=0.f,s3=0.f;
  constexpr int I4 = I & ~3;
#pragma unroll
  for (int j=0;j<I4;j+=4){
    float4 a4 = *(const float4*)&ar[j];
    s0 += a4.x*v[j+0]; s1 += a4.y*v[j+1]; s2 += a4.z*v[j+2]; s3 += a4.w*v[j+3];
  }
#pragma unroll
  for (int j=I4;j<I;j++) s0 += ar[j]*v[j];
  v[I] += (s0+s2)+(s1+s3);
}
template<int I> __device__ __forceinline__ void fsub_all(float* v, const float (*sa)[64]){
  if constexpr (I >= 1){
    fsub_all<I-1>(v, sa);
    fsub_step<I>(v, sa);
  }
}

// ---------------- fp32 -> bf16 cast ----------------
__global__ __launch_bounds__(256) void cast_f2b(
    const float* __restrict__ src, bf16* __restrict__ dst, int n4)
{
  int i = blockIdx.x*256 + threadIdx.x;
  if (i >= n4) return;
  float4 v = *(const float4*)&src[(size_t)i*4];
  float a[4] = {v.x, v.y, v.z, v.w};
  *(uint2*)&dst[(size_t)i*4] = pack_bf4(a);
}

// ---------------- MFMA GEMM tile body: Y[M,N] = X[M,K] @ W[N,K]^T ----------------
// global_load_lds width-16, linear LDS dest, both-sides XOR swizzle (rule #21).
template<typename OUT_T>
__device__ __forceinline__ void gemm_tile_body(
    const bf16* __restrict__ X, const bf16* __restrict__ W,
    OUT_T* __restrict__ Y, int M, int N, int K,
    int bx, int by, int tid, bf16* As, bf16* Bs)
{
  const int wv = tid >> 6;
  const int lane = tid & 63;
  const int row0 = by*128, col0 = bx*128;
  const int mw = (wv&1)*64, nw = (wv>>1)*64;
  const int q = lane >> 4;
  const int l15 = lane & 15;
  const int swr = l15 & 7;
  f32x4 acc[4][4];
#pragma unroll
  for (int mi=0;mi<4;mi++)
#pragma unroll
    for (int ni=0;ni<4;ni++) acc[mi][ni] = (f32x4){0.f,0.f,0.f,0.f};

  const int sr8 = lane >> 3;
  const int scs = ((lane & 7) ^ sr8) * 8;
  for (int k0=0;k0<K;k0+=64){
#pragma unroll
    for (int i=0;i<4;i++){
      __builtin_amdgcn_global_load_lds(
          (const void*)&X[(size_t)(row0 + i*32 + wv*8 + sr8)*K + k0 + scs],
          (void*)&As[i*2048 + wv*512], 16, 0, 0);
      __builtin_amdgcn_global_load_lds(
          (const void*)&W[(size_t)(col0 + i*32 + wv*8 + sr8)*K + k0 + scs],
          (void*)&Bs[i*2048 + wv*512], 16, 0, 0);
    }
    __syncthreads();
#pragma unroll
    for (int ks=0; ks<64; ks+=32){
      bf16x8 af[4], bfr[4];
#pragma unroll
      for (int i=0;i<4;i++){
        const int cc = (((ks>>3) + q) ^ swr) * 8;
        af[i]  = *(const bf16x8*)&As[(mw + i*16 + l15)*64 + cc];
        bfr[i] = *(const bf16x8*)&Bs[(nw + i*16 + l15)*64 + cc];
      }
#pragma unroll
      for (int mi=0;mi<4;mi++)
#pragma unroll
        for (int ni=0;ni<4;ni++)
          acc[mi][ni] = __builtin_amdgcn_mfma_f32_16x16x32_bf16(af[mi], bfr[ni], acc[mi][ni], 0,0,0);
    }
    __syncthreads();
  }
#pragma unroll
  for (int mi=0;mi<4;mi++){
#pragma unroll
    for (int reg=0;reg<4;reg++){
      int row = row0 + mw + mi*16 + q*4 + reg;
#pragma unroll
      for (int ni=0;ni<4;ni++){
        int col = col0 + nw + ni*16 + l15;
        if constexpr (sizeof(OUT_T) == 2)
          Y[(size_t)row*N + col] = (OUT_T)__float2bfloat16(acc[mi][ni][reg]);
        else
          Y[(size_t)row*N + col] = (OUT_T)acc[mi][ni][reg];
      }
    }
  }
}

template<typename OUT_T>
__global__ __launch_bounds__(256) void gemm_bt_mfma(
    const bf16* __restrict__ X, const bf16* __restrict__ W,
    OUT_T* __restrict__ Y, int M, int N, int K)
{
  __shared__ __align__(16) bf16 As[128*64];
  __shared__ __align__(16) bf16 Bs[128*64];
  gemm_tile_body<OUT_T>(X, W, Y, M, N, K, blockIdx.x, blockIdx.y, threadIdx.x, As, Bs);
}

// ------------- beta = sigmoid(x@Wb^T), decay = -exp(A_log)*softplus(x@Wa^T+dt_bias) -------------
__global__ __launch_bounds__(256) void proj_small(
    const float* __restrict__ x, const float* __restrict__ Wb, const float* __restrict__ Wa,
    const float* __restrict__ dt_bias, const float* __restrict__ A_log,
    float* __restrict__ beta_out, float* __restrict__ dec_out)
{
  const int w = threadIdx.x >> 6;
  const int lane = threadIdx.x & 63;
  const int bt = blockIdx.x*4 + w;
  const int b = bt >> 12, t = bt & (T_-1);
  const float* xr = x + (size_t)bt*D_;
  float xv[16];
#pragma unroll
  for (int p=0;p<4;p++){
    float4 v = *(const float4*)&xr[lane*16 + p*4];
    xv[p*4+0]=v.x; xv[p*4+1]=v.y; xv[p*4+2]=v.z; xv[p*4+3]=v.w;
  }
  float accb[H_], acca[H_];
#pragma unroll
  for (int h=0;h<H_;h++){
    float sb=0.f, sa=0.f;
#pragma unroll
    for (int p=0;p<4;p++){
      float4 wb = *(const float4*)&Wb[(size_t)h*D_ + lane*16 + p*4];
      float4 wa = *(const float4*)&Wa[(size_t)h*D_ + lane*16 + p*4];
      sb += xv[p*4+0]*wb.x + xv[p*4+1]*wb.y + xv[p*4+2]*wb.z + xv[p*4+3]*wb.w;
      sa += xv[p*4+0]*wa.x + xv[p*4+1]*wa.y + xv[p*4+2]*wa.z + xv[p*4+3]*wa.w;
    }
    accb[h]=sb; acca[h]=sa;
  }
#pragma unroll
  for (int h=0;h<H_;h++){
#pragma unroll
    for (int m=1;m<64;m<<=1){
      accb[h] += __shfl_xor(accb[h], m, 64);
      acca[h] += __shfl_xor(acca[h], m, 64);
    }
  }
  if (lane < H_) {
    int h = lane;
    beta_out[(size_t)(b*H_+h)*T_ + t] = 1.f/(1.f+expf(-accb[h]));
  } else if (lane < 2*H_) {
    int h = lane - H_;
    float z = acca[h] + dt_bias[h];
    float sp = fmaxf(z,0.f) + log1pf(expf(-fabsf(z)));
    dec_out[(size_t)(b*H_+h)*T_ + t] = -expf(A_log[h]) * sp;
  }
}

// ------------- xinv + fused fp32->bf16 cast of x -------------
__global__ __launch_bounds__(256) void xinv_kernel(
    const float* __restrict__ x, float* __restrict__ xinv, bf16* __restrict__ xb)
{
  const int bt = blockIdx.x;
  const int b = bt >> 12, t = bt & (T_-1);
  const int tid = threadIdx.x;
  float4 xv = *(const float4*)&x[(size_t)bt*D_ + tid*4];
  float a[4] = {xv.x, xv.y, xv.z, xv.w};
  *(uint2*)&xb[(size_t)bt*D_ + tid*4] = pack_bf4(a);
  float ss = xv.x*xv.x + xv.y*xv.y + xv.z*xv.z + xv.w*xv.w;
#pragma unroll
  for (int m=1;m<32;m<<=1) ss += __shfl_xor(ss, m, 32);
  const int h = tid >> 5;
  if ((tid & 31) == 0)
    xinv[(size_t)(b*H_+h)*T_ + t] = rsqrtf(ss + 1e-6f);
}

// ------------- per-chunk cumsum of decay (fp32) -------------
__global__ __launch_bounds__(256) void cumsum_dec(
    const float* __restrict__ dec_raw, float* __restrict__ dec_cum)
{
  int g = blockIdx.x*4 + (threadIdx.x>>6);
  int lane = threadIdx.x & 63;
  float v = sanf(dec_raw[(size_t)g*C_ + lane]);
#pragma unroll
  for (int off=1; off<64; off<<=1){
    float u = __shfl_up(v, off, 64);
    if (lane >= off) v += u;
  }
  dec_cum[(size_t)g*C_ + lane] = v;
}

// ------------- per-chunk prep, MFMA version -------------
__global__ __launch_bounds__(256) void chunk_prep(
    const bf16* __restrict__ xb, const float* __restrict__ xinv,
    const bf16* __restrict__ vpre, const float* __restrict__ cw, const float* __restrict__ cb,
    const float* __restrict__ beta, const float* __restrict__ dec,
    bf16* __restrict__ vchk, bf16* __restrict__ wkc, bf16* __restrict__ attn)
{
  __shared__ __align__(16) bf16 s_x[65][136];    // s_x[r] = x[t0+r-1] raw bf16
  __shared__ __align__(16) float s_a[64][64];    // A matrix (fp32, strict lower)
  __shared__ float s_dec[64], s_beta[64], s_invsh[64], s_negbi[64], s_rsc[64], s_sc2[64];

  const int tid = threadIdx.x;
  const int chunk = blockIdx.x;
  const int bh = chunk >> 6;
  const int nc = chunk & 63;
  const int b = bh >> 3, h = bh & 7;
  const int t0 = nc * C_;
  const size_t xrow = (size_t)b*T_;
  const size_t rowb = (size_t)bh*T_ + t0;
  const size_t kobase = rowb * K_;
  const int w = tid >> 6;
  const int lane = tid & 63;
  const int l15 = lane & 15;
  const int q = lane >> 4;

  for (int idx = tid; idx < 65*16; idx += 256){
    int r = idx >> 4;
    int seg = (idx & 15) * 8;
    int t = t0 + r - 1;
    int tr = t < 0 ? 0 : t;
    *(uint4*)&s_x[r][seg] = *(const uint4*)&xb[(xrow + tr)*D_ + h*K_ + seg];
  }
  if (tid < C_){
    int c = tid;
    float dv  = sanf(dec[rowb + c]);
    float bet = sanf(beta[rowb + c]);
    float invc = sanf(xinv[rowb + c]);
    int tm1 = t0 + c - 1;
    float ivs = (tm1 >= 0) ? sanf(xinv[(size_t)bh*T_ + tm1]) : 0.f;
    s_dec[c] = dv;
    s_beta[c] = bet;
    s_invsh[c] = ivs;
    s_negbi[c] = -bet * ivs;
    s_rsc[c] = invc * 0.08838834764831845f;
    s_sc2[c] = ivs * bet * expn(dv);
  }
  __syncthreads();

  bf16x8 aG[4], aT[4];
#pragma unroll
  for (int ks=0; ks<4; ks++){
    aG[ks] = *(const bf16x8*)&s_x[16*w + l15][ks*32 + q*8];
    aT[ks] = *(const bf16x8*)&s_x[16*w + l15 + 1][ks*32 + q*8];
  }
  f32x4 accG[4], accT[4];
#pragma unroll
  for (int J=0;J<4;J++){ accG[J]=(f32x4){0.f,0.f,0.f,0.f}; accT[J]=(f32x4){0.f,0.f,0.f,0.f}; }
#pragma unroll
  for (int J=0;J<4;J++){
    if (J <= w){
#pragma unroll
      for (int ks=0; ks<4; ks++){
        bf16x8 bfrag = *(const bf16x8*)&s_x[16*J + l15][ks*32 + q*8];
        accG[J] = __builtin_amdgcn_mfma_f32_16x16x32_bf16(aG[ks], bfrag, accG[J], 0,0,0);
        accT[J] = __builtin_amdgcn_mfma_f32_16x16x32_bf16(aT[ks], bfrag, accT[J], 0,0,0);
      }
    }
  }
  {
    const int i0 = 16*w + q*4;
#pragma unroll
    for (int J=0;J<4;J++){
      const int j = 16*J + l15;
#pragma unroll
      for (int reg=0;reg<4;reg++){
        const int i = i0 + reg;
        if (j < i)
          s_a[i][j] = s_negbi[i] * s_invsh[j] * expn(s_dec[i]-s_dec[j]) * accG[J][reg];
        float val = 0.f;
        if (j <= i)
          val = s_rsc[i] * s_invsh[j] * expn(s_dec[i]-s_dec[j]) * accT[J][reg];
        attn[(size_t)chunk*4096 + i*64 + j] = __float2bfloat16(val);
      }
    }
  }

  float v[64];
  if (tid < 128){
    const int col = tid;
    float4 cwv = *(const float4*)&cw[(h*K_+col)*4];
    const float cbv = cb[h*K_+col];
    const bf16* vp = vpre + (xrow + t0)*D_ + h*K_ + col;
    float win0, win1, win2;
    { int t = t0-3; win0 = (t>=0)? sanf(__bfloat162float(vpre[(xrow+t)*D_+h*K_+col])) : 0.f; }
    { int t = t0-2; win1 = (t>=0)? sanf(__bfloat162float(vpre[(xrow+t)*D_+h*K_+col])) : 0.f; }
    { int t = t0-1; win2 = (t>=0)? sanf(__bfloat162float(vpre[(xrow+t)*D_+h*K_+col])) : 0.f; }
#pragma unroll
    for (int c8=0; c8<8; c8++){
      float nv[8];
#pragma unroll
      for (int u=0;u<8;u++) nv[u] = sanf(__bfloat162float(vp[(size_t)(c8*8+u)*D_]));
#pragma unroll
      for (int u=0;u<8;u++){
        const int c = c8*8+u;
        float a = cbv + cwv.x*win0 + cwv.y*win1 + cwv.z*win2 + cwv.w*nv[u];
        v[c] = siluf(a) * s_beta[c];
        win0=win1; win1=win2; win2=nv[u];
      }
    }
  } else {
    const int col = tid - 128;
#pragma unroll
    for (int c=0;c<64;c++)
      v[c] = __bfloat162float(s_x[c][col]) * s_sc2[c];
  }
  __syncthreads();   // s_a complete

  fsub_all<63>(v, s_a);

  {
    const int col = tid & 127;
    bf16* dst = (tid < 128 ? vchk : wkc) + kobase + col;
#pragma unroll
    for (int c=0;c<64;c++)
      dst[(size_t)c*K_] = __float2bfloat16(v[c]);
  }
}

// ------------- scan body: LDS-diet version -------------
// 4 waves, 256 threads. A-operands (wkc/x/attn rows = per-lane MFMA fragments)
// and all scalars load straight from global into registers, prefetched one
// chunk ahead (T14). LDS holds only: xst dbuf (B for S-upd, needs transpose),
// st hi/lo (cross-wave state), vn (cross-wave exchange). 2 BAR_LGKM per chunk.
// LDS = 52.5 KB -> co-residency with gemm blocks in the fused launch.
__device__ void scan_body(
    int sid, int tid, unsigned char* smem,
    const bf16* __restrict__ xb, const float* __restrict__ xinv, bf16* vo,
    const bf16* __restrict__ wkc, const bf16* __restrict__ attn,
    const float* __restrict__ dec)
{
  bf16* xst   = (bf16*)smem;               // [2][128][72]
  bf16* st_hi = (bf16*)(smem + 36864);     // [16][136]
  bf16* st_lo = (bf16*)(smem + 41216);     // [16][136]
  bf16* vn_t  = (bf16*)(smem + 45568);     // [16][72]
  bf16* vn_sh = (bf16*)(smem + 47872);     // [16][72]
  bf16* vn_sl = (bf16*)(smem + 50176);     // [16][72]

  const int bh = sid & 31;
  const int g  = sid >> 5;
  const int b = bh >> 3, h = bh & 7;
  const int j0 = g*16;
  const int w  = tid >> 6;
  const int lane = tid & 63;
  const int l15 = lane & 15;
  const int q = lane >> 4;
  const int wrow = 16*w;
  const int c0 = wrow + q*4;          // this thread's 4 output rows
  const size_t xrow = (size_t)b*T_;
  const size_t bhT = (size_t)bh*T_;

  for (int e=tid; e<16*136; e+=256){
    ((unsigned short*)st_hi)[e] = 0;
    ((unsigned short*)st_lo)[e] = 0;
  }

  const int xc0 = (tid & 31)*2;
  const int xkb = (tid >> 5)*16;

  f32x4 accS[2];
  accS[0] = (f32x4){0.f,0.f,0.f,0.f};
  accS[1] = (f32x4){0.f,0.f,0.f,0.f};

  uint4 T_r[4];                        // xst staging regs (chunk n+1)
  uint4 P_w[4], P_x[4], P_a[2];        // A-operand prefetch (this chunk)
  bf16  P_v[4];
  float4 P_d, P_xi;
  float P_d63, P_xm[4];

  auto issue_t = [&](int c){
    int t0 = c*C_;
    int t1 = t0 + xc0 - 1;
    const bf16* p1 = xb + (xrow + (t1<0?0:t1))*D_ + h*K_ + xkb;
    const bf16* p2 = xb + (xrow + (t0+xc0))*D_ + h*K_ + xkb;
    T_r[0]=*(const uint4*)p1; T_r[1]=*(const uint4*)(p1+8);
    T_r[2]=*(const uint4*)p2; T_r[3]=*(const uint4*)(p2+8);
  };
  auto write_xst = [&](int buf){
    unsigned r1[8]={T_r[0].x,T_r[0].y,T_r[0].z,T_r[0].w,T_r[1].x,T_r[1].y,T_r[1].z,T_r[1].w};
    unsigned r2[8]={T_r[2].x,T_r[2].y,T_r[2].z,T_r[2].w,T_r[3].x,T_r[3].y,T_r[3].z,T_r[3].w};
    bf16* base = xst + buf*(128*72);
#pragma unroll
    for (int i2=0;i2<8;i2++){
      *(unsigned*)&base[(xkb + 2*i2)*72 + xc0]     = (r1[i2] & 0xffffu) | (r2[i2] << 16);
      *(unsigned*)&base[(xkb + 2*i2 + 1)*72 + xc0] = (r1[i2] >> 16) | (r2[i2] & 0xffff0000u);
    }
  };
  auto issue_main = [&](int c){
    int t0 = c*C_;
    size_t rowb = bhT + t0;
    const bf16* pw = wkc + (rowb + wrow + l15)*K_ + q*8;
    const bf16* px = xb + (xrow + t0 + wrow + l15)*D_ + h*K_ + q*8;
#pragma unroll
    for (int ks=0; ks<4; ks++){
      P_w[ks] = *(const uint4*)(pw + ks*32);
      P_x[ks] = *(const uint4*)(px + ks*32);
    }
    const bf16* pv = vo + (rowb + c0)*K_ + j0 + l15;
#pragma unroll
    for (int r=0;r<4;r++) P_v[r] = pv[(size_t)r*K_];
    P_d   = *(const float4*)&dec[rowb + c0];
    P_d63 = dec[rowb + 63];
    P_xi  = *(const float4*)&xinv[bhT + t0 + c0];
#pragma unroll
    for (int r=0;r<4;r++){
      int tm1 = t0 + c0 + r - 1;
      P_xm[r] = (tm1 >= 0) ? xinv[bhT + tm1] : 0.f;
    }
  };
  auto issue_att = [&](int c){
    const bf16* pa = attn + (size_t)(bh*N_CH + c)*4096 + (wrow + l15)*64 + q*8;
    P_a[0] = *(const uint4*)pa;
    P_a[1] = *(const uint4*)(pa + 32);
  };

  // prologue
  issue_t(0);
  write_xst(0);
  issue_t(1);
  issue_main(0);
  issue_att(0);
  BAR_LGKM();

  for (int nc=0; nc<N_CH; nc++){
    const int t0 = nc*C_;
    const size_t rowb = bhT + t0;

    // ---- extract this chunk's scalars / vinit from prefetch regs ----
    float d63s = sanf(P_d63);
    float a63 = expn(d63s);
    float cdA[4] = {sanf(P_d.x), sanf(P_d.y), sanf(P_d.z), sanf(P_d.w)};
    float cxiA[4] = {sanf(P_xi.x), sanf(P_xi.y), sanf(P_xi.z), sanf(P_xi.w)};
    float sov[4], scv[4], vinitf[4];
#pragma unroll
    for (int r=0;r<4;r++){
      sov[r] = cxiA[r] * 0.08838834764831845f * expn(cdA[r]);
      scv[r] = sanf(P_xm[r]) * expn(d63s - cdA[r]);
      vinitf[r] = __bfloat162float(P_v[r]);
    }

    // ---- stage xst for chunk nc+1 (buf flips), reissue xst loads ----
    write_xst((nc+1)&1);
    issue_t(nc+2 < N_CH ? nc+2 : N_CH-1);

    // ---- phase B: accV = v - wkc@S ; accP = x@S (A from regs) ----
    f32x4 accV, accP = (f32x4){0.f,0.f,0.f,0.f};
#pragma unroll
    for (int r=0;r<4;r++) accV[r] = vinitf[r];
    __builtin_amdgcn_s_setprio(1);
#pragma unroll
    for (int ks=0; ks<4; ks++){
      bf16x8 bh_ = *(const bf16x8*)&st_hi[l15*136 + ks*32 + q*8];
      bf16x8 bl_ = *(const bf16x8*)&st_lo[l15*136 + ks*32 + q*8];
      uint4 uw = P_w[ks];
      uw.x ^= 0x80008000u; uw.y ^= 0x80008000u; uw.z ^= 0x80008000u; uw.w ^= 0x80008000u;
      bf16x8 a1 = u4_to_b8(uw);
      bf16x8 a2 = u4_to_b8(P_x[ks]);
      accV = __builtin_amdgcn_mfma_f32_16x16x32_bf16(a1, bh_, accV, 0,0,0);
      accV = __builtin_amdgcn_mfma_f32_16x16x32_bf16(a1, bl_, accV, 0,0,0);
      accP = __builtin_amdgcn_mfma_f32_16x16x32_bf16(a2, bh_, accP, 0,0,0);
      accP = __builtin_amdgcn_mfma_f32_16x16x32_bf16(a2, bl_, accP, 0,0,0);
    }
    __builtin_amdgcn_s_setprio(0);
    f32x4 oacc;
#pragma unroll
    for (int r=0;r<4;r++) oacc[r] = accP[r] * sov[r];
    {
      float v4[4] = {accV[0],accV[1],accV[2],accV[3]};
      *(uint2*)&vn_t[l15*72 + c0] = pack_bf4(v4);
      float vs[4];
#pragma unroll
      for (int r=0;r<4;r++) vs[r] = accV[r] * scv[r];
      uint2 ph = pack_bf4(vs);
      float lo4[4];
      lo4[0] = vs[0] - __uint_as_float(ph.x << 16);
      lo4[1] = vs[1] - __uint_as_float(ph.x & 0xffff0000u);
      lo4[2] = vs[2] - __uint_as_float(ph.y << 16);
      lo4[3] = vs[3] - __uint_as_float(ph.y & 0xffff0000u);
      *(uint2*)&vn_sh[l15*72 + c0] = ph;
      *(uint2*)&vn_sl[l15*72 + c0] = pack_bf4(lo4);
    }
    // reissue main prefetches for nc+1 (loads fly across the barrier)
    issue_main(nc+1 < N_CH ? nc+1 : N_CH-1);
    BAR_LGKM();   // b2: vn ready

    // ---- phase C: o = P*sov + attn@vn, store; S = a63*S + (vn*scv)^T @ xst ----
    __builtin_amdgcn_s_setprio(1);
#pragma unroll
    for (int ks=0; ks<2; ks++){
      bf16x8 bV = *(const bf16x8*)&vn_t[l15*72 + ks*32 + q*8];
      bf16x8 aA = u4_to_b8(P_a[ks]);
      oacc = __builtin_amdgcn_mfma_f32_16x16x32_bf16(aA, bV, oacc, 0,0,0);
    }
    __builtin_amdgcn_s_setprio(0);
    {
      bf16* po = vo + (rowb + c0)*K_ + j0 + l15;
#pragma unroll
      for (int r=0;r<4;r++) po[(size_t)r*K_] = __float2bfloat16(oacc[r]);
    }
    issue_att(nc+1 < N_CH ? nc+1 : N_CH-1);
    __builtin_amdgcn_s_setprio(1);
    {
      bf16x8 aH[2], aL[2];
#pragma unroll
      for (int ks=0; ks<2; ks++){
        aH[ks] = *(const bf16x8*)&vn_sh[l15*72 + ks*32 + q*8];
        aL[ks] = *(const bf16x8*)&vn_sl[l15*72 + ks*32 + q*8];
      }
      const bf16* xcur = xst + (nc&1)*(128*72);
#pragma unroll
      for (int sub=0; sub<2; sub++){
        f32x4 acc = accS[sub];
#pragma unroll
        for (int r=0;r<4;r++) acc[r] *= a63;
#pragma unroll
        for (int ks=0; ks<2; ks++){
          bf16x8 bX = *(const bf16x8*)&xcur[(32*w + 16*sub + l15)*72 + ks*32 + q*8];
          acc = __builtin_amdgcn_mfma_f32_16x16x32_bf16(aH[ks], bX, acc, 0,0,0);
          acc = __builtin_amdgcn_mfma_f32_16x16x32_bf16(aL[ks], bX, acc, 0,0,0);
        }
        accS[sub] = acc;
#pragma unroll
        for (int r=0;r<4;r++){
          float sv = acc[r];
          bf16 hb = __float2bfloat16(sv);
          st_hi[(q*4+r)*136 + 32*w + 16*sub + l15] = hb;
          st_lo[(q*4+r)*136 + 32*w + 16*sub + l15] = __float2bfloat16(sv - __bfloat162float(hb));
        }
      }
    }
    __builtin_amdgcn_s_setprio(0);
    BAR_LGKM();   // b3: st + next xst buf ready
  }
}

// ------------- fused launch: scan blocks (bid%5==0) + gate GEMM blocks -------------
// scan LDS 52.5 KB -> 3 blocks/CU: 1 scan + 2 gemm co-resident; gemm waves
// fill scan's latency stalls. bid%5 spreads the 256 scan blocks 1-per-CU under
// round-robin dispatch (gcd(5,256)=1). No cross-block dependencies.
__global__ __launch_bounds__(256) void scan_gate_kernel(
    const bf16* __restrict__ xb, const float* __restrict__ xinv, bf16* vo,
    const bf16* __restrict__ wkc, const bf16* __restrict__ attn,
    const float* __restrict__ dec,
    const bf16* __restrict__ Wgb, bf16* __restrict__ gate)
{
  __shared__ __align__(16) unsigned char smem[52480];
  const int bid = blockIdx.x;
  const int tid = threadIdx.x;
  if (bid % 5 == 0){
    scan_body(bid/5, tid, smem, xb, xinv, vo, wkc, attn, dec);
  } else {
    int gid = bid - bid/5 - 1;          // 0..1023
    int bx = gid & 7, by = gid >> 3;
    gemm_tile_body<bf16>(xb, Wgb, gate, BT_, D_, D_, bx, by, tid,
                         (bf16*)smem, (bf16*)(smem + 16384));
  }
}

// ------------- per-head RMSNorm * norm_w * silu(gate); gate buffer overwritten in place -------------
__global__ __launch_bounds__(256) void norm_gate(
    const bf16* __restrict__ o, bf16* gio, const float* __restrict__ norm_w)
{
  const int bt = blockIdx.x;
  const int b = bt >> 12, t = bt & (T_-1);
  const int tid = threadIdx.x;
  const int h = tid >> 5;
  const int kk = (tid & 31)*4;
  float ov[4];
  ld_bf4s(o + ((size_t)(b*H_+h)*T_ + t)*K_ + kk, ov);
  float ss = ov[0]*ov[0] + ov[1]*ov[1] + ov[2]*ov[2] + ov[3]*ov[3];
#pragma unroll
  for (int m=1;m<32;m<<=1) ss += __shfl_xor(ss, m, 32);
  float r = rsqrtf(ss*(1.f/128.f) + 1e-5f);
  float4 nw = *(const float4*)&norm_w[kk];
  float gv[4];
  ld_bf4s(gio + (size_t)bt*D_ + tid*4, gv);
  float res[4];
  res[0] = ov[0]*r*nw.x * siluf(gv[0]);
  res[1] = ov[1]*r*nw.y * siluf(gv[1]);
  res[2] = ov[2]*r*nw.z * siluf(gv[2]);
  res[3] = ov[3]*r*nw.w * siluf(gv[3]);
  *(uint2*)&gio[(size_t)bt*D_ + tid*4] = pack_bf4(res);
}

extern "C" void kernel_launch(void* const* d_in, const int* in_sizes, int n_in,
                              void* d_out, int out_size, void* d_ws, size_t ws_size,
                              hipStream_t stream)
{
  const float* x       = (const float*)d_in[0];
  const float* Wv      = (const float*)d_in[1];
  const float* Wg      = (const float*)d_in[2];
  const float* Wo      = (const float*)d_in[3];
  const float* Wb      = (const float*)d_in[4];
  const float* Wa      = (const float*)d_in[5];
  const float* dt_bias = (const float*)d_in[6];
  const float* A_log   = (const float*)d_in[7];
  const float* norm_w  = (const float*)d_in[8];
  const float* conv_w  = (const float*)d_in[9];
  const float* conv_b  = (const float*)d_in[10];
  float* out = (float*)d_out;

  const size_t BTD = (size_t)B_*T_*D_;
  const size_t BHT = (size_t)B_*H_*T_;
  const size_t DD  = (size_t)D_*D_;

  // ws layout (~108.6 MB): fp32 smalls, bf16 weight copies, then big bf16 buffers
  float* beta = (float*)d_ws;          // 0.5 MiB each
  float* decr = beta + BHT;
  float* decc = decr + BHT;
  float* xinv = decc + BHT;
  bf16* Wvb = (bf16*)(xinv + BHT);     // 2 MiB each
  bf16* Wgb = Wvb + DD;
  bf16* Wob = Wgb + DD;
  bf16* xb   = Wob + DD;               // 33.5 MiB: bf16 copy of x
  bf16* vpre = xb + BTD;               // 33.5 MiB: Wv-GEMM out; later gate/og
  bf16* wkc  = vpre + BTD;             // 33.5 MiB
  // d_out (67 MB fp32) hosts: [vchk->o bf16: BTD][attn bf16: BTD/2]
  bf16* vo   = (bf16*)d_out;
  bf16* attn = vo + BTD;

  dim3 gemm_grid(D_/128, BT_/128);   // (8, 128)
  xinv_kernel<<<BT_, 256, 0, stream>>>(x, xinv, xb);   // fused fp32->bf16 cast of x
  cast_f2b<<<(DD/4+255)/256, 256, 0, stream>>>(Wv, Wvb, DD/4);
  cast_f2b<<<(DD/4+255)/256, 256, 0, stream>>>(Wg, Wgb, DD/4);
  cast_f2b<<<(DD/4+255)/256, 256, 0, stream>>>(Wo, Wob, DD/4);
  gemm_bt_mfma<bf16><<<gemm_grid, 256, 0, stream>>>(xb, Wvb, vpre, BT_, D_, D_);
  proj_small<<<BT_/4, 256, 0, stream>>>(x, Wb, Wa, dt_bias, A_log, beta, decr);
  cumsum_dec<<<(BHT/C_)/4, 256, 0, stream>>>(decr, decc);
  chunk_prep<<<B_*H_*N_CH, 256, 0, stream>>>(xb, xinv, vpre, conv_w, conv_b,
                                             beta, decc, vo /*vchk*/, wkc, attn);
  // fused: scan (256 blocks) + gate GEMM (1024 blocks) in one launch.
  // gate GEMM is independent of scan; its waves hide scan's latency stalls.
  scan_gate_kernel<<<1280, 256, 0, stream>>>(xb, xinv, vo, wkc, attn, decc,
                                             Wgb, vpre /*gate*/);
  norm_gate<<<BT_, 256, 0, stream>>>(vo /*o*/, vpre /*gate->og*/, norm_w);
  gemm_bt_mfma<float><<<gemm_grid, 256, 0, stream>>>(vpre, Wob, out, BT_, D_, D_);
}

// Round 9
// 618.851 us; speedup vs baseline: 1.1825x; 1.1825x over previous
//
#include <hip/hip_runtime.h>
#include <hip/hip_bf16.h>
#include <math.h>

#define H_ 8
#define K_ 128
#define C_ 64
#define D_ 1024
#define T_ 4096
#define B_ 4
#define N_CH 64           // T_/C_
#define BT_ (B_*T_)

typedef __attribute__((ext_vector_type(8))) short bf16x8;
typedef __attribute__((ext_vector_type(4))) float f32x4;
typedef __hip_bfloat16 bf16;

// raw barrier: order LDS (lgkm) only; leave global loads/stores in flight (T4)
#define BAR_LGKM() do { \
  asm volatile("s_waitcnt lgkmcnt(0)" ::: "memory"); \
  __builtin_amdgcn_sched_barrier(0); \
  __builtin_amdgcn_s_barrier(); \
} while(0)

__device__ __forceinline__ float siluf(float x){ return x / (1.0f + expf(-x)); }
__device__ __forceinline__ float expn(float x){ return expf(fminf(x, 0.f)); }
__device__ __forceinline__ float sanf(float v){ return (__builtin_fabsf(v) <= 1e30f) ? v : 0.f; }

__device__ __forceinline__ void ld_bf4(const bf16* p, float* o){
  uint2 u = *(const uint2*)p;
  o[0]=__uint_as_float(u.x<<16); o[1]=__uint_as_float(u.x&0xffff0000u);
  o[2]=__uint_as_float(u.y<<16); o[3]=__uint_as_float(u.y&0xffff0000u);
}
__device__ __forceinline__ void ld_bf4s(const bf16* p, float* o){
  ld_bf4(p, o);
#pragma unroll
  for (int e=0;e<4;e++) o[e] = sanf(o[e]);
}
__device__ __forceinline__ unsigned short f2bfu(float f){
  bf16 h = __float2bfloat16(f);
  return *reinterpret_cast<unsigned short*>(&h);
}
__device__ __forceinline__ uint2 pack_bf4(const float* v){
  uint2 r;
  r.x = (unsigned)f2bfu(v[0]) | ((unsigned)f2bfu(v[1])<<16);
  r.y = (unsigned)f2bfu(v[2]) | ((unsigned)f2bfu(v[3])<<16);
  return r;
}
__device__ __forceinline__ bf16x8 u4_to_b8(uint4 u){
  union { uint4 u; bf16x8 b; } cv; cv.u = u; return cv.b;
}

// ---- fully-unrolled forward substitution (template-const indices: rule #20) ----
template<int I> __device__ __forceinline__ void fsub_step(float* v, const float (*sa)[64]){
  const float* ar = sa[I];
  float s0=0.f,s1=0.f,s2=0.f,s3=0.f;
  constexpr int I4 = I & ~3;
#pragma unroll
  for (int j=0;j<I4;j+=4){
    float4 a4 = *(const float4*)&ar[j];
    s0 += a4.x*v[j+0]; s1 += a4.y*v[j+1]; s2 += a4.z*v[j+2]; s3 += a4.w*v[j+3];
  }
#pragma unroll
  for (int j=I4;j<I;j++) s0 += ar[j]*v[j];
  v[I] += (s0+s2)+(s1+s3);
}
template<int I> __device__ __forceinline__ void fsub_all(float* v, const float (*sa)[64]){
  if constexpr (I >= 1){
    fsub_all<I-1>(v, sa);
    fsub_step<I>(v, sa);
  }
}

// ---------------- fp32 -> bf16 cast ----------------
__global__ __launch_bounds__(256) void cast_f2b(
    const float* __restrict__ src, bf16* __restrict__ dst, int n4)
{
  int i = blockIdx.x*256 + threadIdx.x;
  if (i >= n4) return;
  float4 v = *(const float4*)&src[(size_t)i*4];
  float a[4] = {v.x, v.y, v.z, v.w};
  *(uint2*)&dst[(size_t)i*4] = pack_bf4(a);
}

// ---------------- MFMA GEMM: Y[M,N] = X[M,K](bf16) @ W[N,K](bf16)^T ----------------
// global_load_lds width-16 staging, linear LDS dest, both-sides XOR swizzle
// (rule #21). FUSE_NG: fused per-head RMSNorm * norm_w * silu(gate) epilogue
// (gate GEMM; grid.x == H_, each block covers exactly one head's 128 cols).
template<typename OUT_T, bool FUSE_NG>
__global__ __launch_bounds__(256) void gemm_bt_mfma(
    const bf16* __restrict__ X, const bf16* __restrict__ W,
    OUT_T* __restrict__ Y, int M, int N, int K,
    const bf16* __restrict__ o_in, const float* __restrict__ norm_w)
{
  __shared__ __align__(16) bf16 As[128*64];
  __shared__ __align__(16) bf16 Bs[128*64];
  const int tid = threadIdx.x;
  const int wv = tid >> 6;
  const int lane = tid & 63;
  const int row0 = blockIdx.y*128, col0 = blockIdx.x*128;
  const int mw = (wv&1)*64, nw = (wv>>1)*64;
  const int q = lane >> 4;
  const int l15 = lane & 15;
  const int swr = l15 & 7;
  f32x4 acc[4][4];
#pragma unroll
  for (int mi=0;mi<4;mi++)
#pragma unroll
    for (int ni=0;ni<4;ni++) acc[mi][ni] = (f32x4){0.f,0.f,0.f,0.f};

  const int sr8 = lane >> 3;
  const int scs = ((lane & 7) ^ sr8) * 8;
  for (int k0=0;k0<K;k0+=64){
#pragma unroll
    for (int i=0;i<4;i++){
      __builtin_amdgcn_global_load_lds(
          (const void*)&X[(size_t)(row0 + i*32 + wv*8 + sr8)*K + k0 + scs],
          (void*)&As[i*2048 + wv*512], 16, 0, 0);
      __builtin_amdgcn_global_load_lds(
          (const void*)&W[(size_t)(col0 + i*32 + wv*8 + sr8)*K + k0 + scs],
          (void*)&Bs[i*2048 + wv*512], 16, 0, 0);
    }
    __syncthreads();
#pragma unroll
    for (int ks=0; ks<64; ks+=32){
      bf16x8 af[4], bfr[4];
#pragma unroll
      for (int i=0;i<4;i++){
        const int cc = (((ks>>3) + q) ^ swr) * 8;
        af[i]  = *(const bf16x8*)&As[(mw + i*16 + l15)*64 + cc];
        bfr[i] = *(const bf16x8*)&Bs[(nw + i*16 + l15)*64 + cc];
      }
#pragma unroll
      for (int mi=0;mi<4;mi++)
#pragma unroll
        for (int ni=0;ni<4;ni++)
          acc[mi][ni] = __builtin_amdgcn_mfma_f32_16x16x32_bf16(af[mi], bfr[ni], acc[mi][ni], 0,0,0);
    }
    __syncthreads();
  }

  if constexpr (FUSE_NG){
    // ---- fused RMSNorm(o)*norm_w*silu(gate) -> og ----
    float* s_red = (float*)As;          // 256 floats; As dead after last sync
    const int hh = blockIdx.x;          // head (grid.x == H_)
    const int nwh = nw >> 6;            // 0 or 1
#pragma unroll
    for (int mi=0;mi<4;mi++){
#pragma unroll
      for (int reg=0;reg<4;reg++){
        int row = row0 + mw + mi*16 + q*4 + reg;
        int b = row >> 12, t = row & (T_-1);
        const bf16* orow = o_in + ((size_t)(b*H_+hh)*T_ + t)*K_;
        float ps = 0.f;
#pragma unroll
        for (int ni=0;ni<4;ni++){
          float ov = sanf(__bfloat162float(orow[nw + ni*16 + l15]));
          ps += ov*ov;
        }
        ps += __shfl_xor(ps,1,64); ps += __shfl_xor(ps,2,64);
        ps += __shfl_xor(ps,4,64); ps += __shfl_xor(ps,8,64);
        if (l15 == 0) s_red[nwh*128 + mw + mi*16 + q*4 + reg] = ps;
      }
    }
    __syncthreads();
#pragma unroll
    for (int mi=0;mi<4;mi++){
#pragma unroll
      for (int reg=0;reg<4;reg++){
        int lr = mw + mi*16 + q*4 + reg;
        float ssum = s_red[lr] + s_red[128 + lr];
        float rr = rsqrtf(ssum*(1.f/128.f) + 1e-5f);
        int row = row0 + lr;
        int b = row >> 12, t = row & (T_-1);
        const bf16* orow = o_in + ((size_t)(b*H_+hh)*T_ + t)*K_;
#pragma unroll
        for (int ni=0;ni<4;ni++){
          int k = nw + ni*16 + l15;
          float ov = sanf(__bfloat162float(orow[k]));
          float res = ov * rr * norm_w[k] * siluf(acc[mi][ni][reg]);
          Y[(size_t)row*N + col0 + k] = (OUT_T)__float2bfloat16(res);
        }
      }
    }
  } else {
#pragma unroll
    for (int mi=0;mi<4;mi++){
#pragma unroll
      for (int reg=0;reg<4;reg++){
        int row = row0 + mw + mi*16 + q*4 + reg;
#pragma unroll
        for (int ni=0;ni<4;ni++){
          int col = col0 + nw + ni*16 + l15;
          if constexpr (sizeof(OUT_T) == 2)
            Y[(size_t)row*N + col] = (OUT_T)__float2bfloat16(acc[mi][ni][reg]);
          else
            Y[(size_t)row*N + col] = (OUT_T)acc[mi][ni][reg];
        }
      }
    }
  }
}

// ------------- beta = sigmoid(x@Wb^T), decay = -exp(A_log)*softplus(x@Wa^T+dt_bias) -------------
__global__ __launch_bounds__(256) void proj_small(
    const float* __restrict__ x, const float* __restrict__ Wb, const float* __restrict__ Wa,
    const float* __restrict__ dt_bias, const float* __restrict__ A_log,
    float* __restrict__ beta_out, float* __restrict__ dec_out)
{
  const int w = threadIdx.x >> 6;
  const int lane = threadIdx.x & 63;
  const int bt = blockIdx.x*4 + w;
  const int b = bt >> 12, t = bt & (T_-1);
  const float* xr = x + (size_t)bt*D_;
  float xv[16];
#pragma unroll
  for (int p=0;p<4;p++){
    float4 v = *(const float4*)&xr[lane*16 + p*4];
    xv[p*4+0]=v.x; xv[p*4+1]=v.y; xv[p*4+2]=v.z; xv[p*4+3]=v.w;
  }
  float accb[H_], acca[H_];
#pragma unroll
  for (int h=0;h<H_;h++){
    float sb=0.f, sa=0.f;
#pragma unroll
    for (int p=0;p<4;p++){
      float4 wb = *(const float4*)&Wb[(size_t)h*D_ + lane*16 + p*4];
      float4 wa = *(const float4*)&Wa[(size_t)h*D_ + lane*16 + p*4];
      sb += xv[p*4+0]*wb.x + xv[p*4+1]*wb.y + xv[p*4+2]*wb.z + xv[p*4+3]*wb.w;
      sa += xv[p*4+0]*wa.x + xv[p*4+1]*wa.y + xv[p*4+2]*wa.z + xv[p*4+3]*wa.w;
    }
    accb[h]=sb; acca[h]=sa;
  }
#pragma unroll
  for (int h=0;h<H_;h++){
#pragma unroll
    for (int m=1;m<64;m<<=1){
      accb[h] += __shfl_xor(accb[h], m, 64);
      acca[h] += __shfl_xor(acca[h], m, 64);
    }
  }
  if (lane < H_) {
    int h = lane;
    beta_out[(size_t)(b*H_+h)*T_ + t] = 1.f/(1.f+expf(-accb[h]));
  } else if (lane < 2*H_) {
    int h = lane - H_;
    float z = acca[h] + dt_bias[h];
    float sp = fmaxf(z,0.f) + log1pf(expf(-fabsf(z)));
    dec_out[(size_t)(b*H_+h)*T_ + t] = -expf(A_log[h]) * sp;
  }
}

// ------------- xinv + fused fp32->bf16 cast of x -------------
__global__ __launch_bounds__(256) void xinv_kernel(
    const float* __restrict__ x, float* __restrict__ xinv, bf16* __restrict__ xb)
{
  const int bt = blockIdx.x;
  const int b = bt >> 12, t = bt & (T_-1);
  const int tid = threadIdx.x;
  float4 xv = *(const float4*)&x[(size_t)bt*D_ + tid*4];
  float a[4] = {xv.x, xv.y, xv.z, xv.w};
  *(uint2*)&xb[(size_t)bt*D_ + tid*4] = pack_bf4(a);
  float ss = xv.x*xv.x + xv.y*xv.y + xv.z*xv.z + xv.w*xv.w;
#pragma unroll
  for (int m=1;m<32;m<<=1) ss += __shfl_xor(ss, m, 32);
  const int h = tid >> 5;
  if ((tid & 31) == 0)
    xinv[(size_t)(b*H_+h)*T_ + t] = rsqrtf(ss + 1e-6f);
}

// ------------- per-chunk cumsum of decay (fp32) -------------
__global__ __launch_bounds__(256) void cumsum_dec(
    const float* __restrict__ dec_raw, float* __restrict__ dec_cum)
{
  int g = blockIdx.x*4 + (threadIdx.x>>6);
  int lane = threadIdx.x & 63;
  float v = sanf(dec_raw[(size_t)g*C_ + lane]);
#pragma unroll
  for (int off=1; off<64; off<<=1){
    float u = __shfl_up(v, off, 64);
    if (lane >= off) v += u;
  }
  dec_cum[(size_t)g*C_ + lane] = v;
}

// ------------- per-chunk prep, MFMA version -------------
__global__ __launch_bounds__(256) void chunk_prep(
    const bf16* __restrict__ xb, const float* __restrict__ xinv,
    const bf16* __restrict__ vpre, const float* __restrict__ cw, const float* __restrict__ cb,
    const float* __restrict__ beta, const float* __restrict__ dec,
    bf16* __restrict__ vchk, bf16* __restrict__ wkc, bf16* __restrict__ attn)
{
  __shared__ __align__(16) bf16 s_x[65][136];    // s_x[r] = x[t0+r-1] raw bf16
  __shared__ __align__(16) float s_a[64][64];    // A matrix (fp32, strict lower)
  __shared__ float s_dec[64], s_beta[64], s_invsh[64], s_negbi[64], s_rsc[64], s_sc2[64];

  const int tid = threadIdx.x;
  const int chunk = blockIdx.x;
  const int bh = chunk >> 6;
  const int nc = chunk & 63;
  const int b = bh >> 3, h = bh & 7;
  const int t0 = nc * C_;
  const size_t xrow = (size_t)b*T_;
  const size_t rowb = (size_t)bh*T_ + t0;
  const size_t kobase = rowb * K_;
  const int w = tid >> 6;
  const int lane = tid & 63;
  const int l15 = lane & 15;
  const int q = lane >> 4;

  for (int idx = tid; idx < 65*16; idx += 256){
    int r = idx >> 4;
    int seg = (idx & 15) * 8;
    int t = t0 + r - 1;
    int tr = t < 0 ? 0 : t;
    *(uint4*)&s_x[r][seg] = *(const uint4*)&xb[(xrow + tr)*D_ + h*K_ + seg];
  }
  if (tid < C_){
    int c = tid;
    float dv  = sanf(dec[rowb + c]);
    float bet = sanf(beta[rowb + c]);
    float invc = sanf(xinv[rowb + c]);
    int tm1 = t0 + c - 1;
    float ivs = (tm1 >= 0) ? sanf(xinv[(size_t)bh*T_ + tm1]) : 0.f;
    s_dec[c] = dv;
    s_beta[c] = bet;
    s_invsh[c] = ivs;
    s_negbi[c] = -bet * ivs;
    s_rsc[c] = invc * 0.08838834764831845f;
    s_sc2[c] = ivs * bet * expn(dv);
  }
  __syncthreads();

  bf16x8 aG[4], aT[4];
#pragma unroll
  for (int ks=0; ks<4; ks++){
    aG[ks] = *(const bf16x8*)&s_x[16*w + l15][ks*32 + q*8];
    aT[ks] = *(const bf16x8*)&s_x[16*w + l15 + 1][ks*32 + q*8];
  }
  f32x4 accG[4], accT[4];
#pragma unroll
  for (int J=0;J<4;J++){ accG[J]=(f32x4){0.f,0.f,0.f,0.f}; accT[J]=(f32x4){0.f,0.f,0.f,0.f}; }
#pragma unroll
  for (int J=0;J<4;J++){
    if (J <= w){
#pragma unroll
      for (int ks=0; ks<4; ks++){
        bf16x8 bfrag = *(const bf16x8*)&s_x[16*J + l15][ks*32 + q*8];
        accG[J] = __builtin_amdgcn_mfma_f32_16x16x32_bf16(aG[ks], bfrag, accG[J], 0,0,0);
        accT[J] = __builtin_amdgcn_mfma_f32_16x16x32_bf16(aT[ks], bfrag, accT[J], 0,0,0);
      }
    }
  }
  {
    const int i0 = 16*w + q*4;
#pragma unroll
    for (int J=0;J<4;J++){
      const int j = 16*J + l15;
#pragma unroll
      for (int reg=0;reg<4;reg++){
        const int i = i0 + reg;
        if (j < i)
          s_a[i][j] = s_negbi[i] * s_invsh[j] * expn(s_dec[i]-s_dec[j]) * accG[J][reg];
        float val = 0.f;
        if (j <= i)
          val = s_rsc[i] * s_invsh[j] * expn(s_dec[i]-s_dec[j]) * accT[J][reg];
        attn[(size_t)chunk*4096 + i*64 + j] = __float2bfloat16(val);
      }
    }
  }

  float v[64];
  if (tid < 128){
    const int col = tid;
    float4 cwv = *(const float4*)&cw[(h*K_+col)*4];
    const float cbv = cb[h*K_+col];
    const bf16* vp = vpre + (xrow + t0)*D_ + h*K_ + col;
    float win0, win1, win2;
    { int t = t0-3; win0 = (t>=0)? sanf(__bfloat162float(vpre[(xrow+t)*D_+h*K_+col])) : 0.f; }
    { int t = t0-2; win1 = (t>=0)? sanf(__bfloat162float(vpre[(xrow+t)*D_+h*K_+col])) : 0.f; }
    { int t = t0-1; win2 = (t>=0)? sanf(__bfloat162float(vpre[(xrow+t)*D_+h*K_+col])) : 0.f; }
#pragma unroll
    for (int c8=0; c8<8; c8++){
      float nv[8];
#pragma unroll
      for (int u=0;u<8;u++) nv[u] = sanf(__bfloat162float(vp[(size_t)(c8*8+u)*D_]));
#pragma unroll
      for (int u=0;u<8;u++){
        const int c = c8*8+u;
        float a = cbv + cwv.x*win0 + cwv.y*win1 + cwv.z*win2 + cwv.w*nv[u];
        v[c] = siluf(a) * s_beta[c];
        win0=win1; win1=win2; win2=nv[u];
      }
    }
  } else {
    const int col = tid - 128;
#pragma unroll
    for (int c=0;c<64;c++)
      v[c] = __bfloat162float(s_x[c][col]) * s_sc2[c];
  }
  __syncthreads();   // s_a complete

  fsub_all<63>(v, s_a);

  {
    const int col = tid & 127;
    bf16* dst = (tid < 128 ? vchk : wkc) + kobase + col;
#pragma unroll
    for (int c=0;c<64;c++)
      dst[(size_t)c*K_] = __float2bfloat16(v[c]);
  }
}

// ------------- sequential chunk scan: LDS-diet, standalone -------------
// Grid 256 (bh = bid&31 -> the 8 column-group siblings of each bh share one
// XCD's L2 under round-robin dispatch: bid mod 8 == bh mod 8). 4 waves.
// A-operands (wkc/x/attn rows = per-lane MFMA fragments) and all scalars load
// straight from global into registers, prefetched one chunk ahead (T14);
// direct loads are L2-hits thanks to the sibling locality (R8's fusion broke
// exactly this -> 370 MB HBM fetch; standalone restores it). LDS holds only
// xst dbuf + st hi/lo + vn exchange (52.5 KB). 2 lgkm-only barriers/chunk.
__global__ __launch_bounds__(256) void scan_kernel(
    const bf16* __restrict__ xb, const float* __restrict__ xinv, bf16* vo,
    const bf16* __restrict__ wkc, const bf16* __restrict__ attn,
    const float* __restrict__ dec)
{
  __shared__ __align__(16) bf16 xst[2][128][72];
  __shared__ __align__(16) bf16 st_hi[16][136];
  __shared__ __align__(16) bf16 st_lo[16][136];
  __shared__ __align__(16) bf16 vn_t [16][72];
  __shared__ __align__(16) bf16 vn_sh[16][72];
  __shared__ __align__(16) bf16 vn_sl[16][72];

  const int tid = threadIdx.x;
  const int bh = blockIdx.x & 31;
  const int g  = blockIdx.x >> 5;
  const int b = bh >> 3, h = bh & 7;
  const int j0 = g*16;
  const int w  = tid >> 6;
  const int lane = tid & 63;
  const int l15 = lane & 15;
  const int q = lane >> 4;
  const int wrow = 16*w;
  const int c0 = wrow + q*4;          // this thread's 4 output rows
  const size_t xrow = (size_t)b*T_;
  const size_t bhT = (size_t)bh*T_;

  for (int e=tid; e<16*136; e+=256){
    ((unsigned short*)&st_hi[0][0])[e] = 0;
    ((unsigned short*)&st_lo[0][0])[e] = 0;
  }

  const int xc0 = (tid & 31)*2;
  const int xkb = (tid >> 5)*16;

  f32x4 accS[2];
  accS[0] = (f32x4){0.f,0.f,0.f,0.f};
  accS[1] = (f32x4){0.f,0.f,0.f,0.f};

  uint4 T_r[4];                        // xst staging regs (chunk n+1)
  uint4 P_w[4], P_x[4], P_a[2];        // A-operand prefetch (this chunk)
  bf16  P_v[4];
  float4 P_d, P_xi;
  float P_d63, P_xm[4];

  auto issue_t = [&](int c){
    int t0 = c*C_;
    int t1 = t0 + xc0 - 1;
    const bf16* p1 = xb + (xrow + (t1<0?0:t1))*D_ + h*K_ + xkb;
    const bf16* p2 = xb + (xrow + (t0+xc0))*D_ + h*K_ + xkb;
    T_r[0]=*(const uint4*)p1; T_r[1]=*(const uint4*)(p1+8);
    T_r[2]=*(const uint4*)p2; T_r[3]=*(const uint4*)(p2+8);
  };
  auto write_xst = [&](int buf){
    unsigned r1[8]={T_r[0].x,T_r[0].y,T_r[0].z,T_r[0].w,T_r[1].x,T_r[1].y,T_r[1].z,T_r[1].w};
    unsigned r2[8]={T_r[2].x,T_r[2].y,T_r[2].z,T_r[2].w,T_r[3].x,T_r[3].y,T_r[3].z,T_r[3].w};
#pragma unroll
    for (int i2=0;i2<8;i2++){
      *(unsigned*)&xst[buf][xkb + 2*i2][xc0]     = (r1[i2] & 0xffffu) | (r2[i2] << 16);
      *(unsigned*)&xst[buf][xkb + 2*i2 + 1][xc0] = (r1[i2] >> 16) | (r2[i2] & 0xffff0000u);
    }
  };
  auto issue_main = [&](int c){
    int t0 = c*C_;
    size_t rowb = bhT + t0;
    const bf16* pw = wkc + (rowb + wrow + l15)*K_ + q*8;
    const bf16* px = xb + (xrow + t0 + wrow + l15)*D_ + h*K_ + q*8;
#pragma unroll
    for (int ks=0; ks<4; ks++){
      P_w[ks] = *(const uint4*)(pw + ks*32);
      P_x[ks] = *(const uint4*)(px + ks*32);
    }
    const bf16* pv = vo + (rowb + c0)*K_ + j0 + l15;
#pragma unroll
    for (int r=0;r<4;r++) P_v[r] = pv[(size_t)r*K_];
    P_d   = *(const float4*)&dec[rowb + c0];
    P_d63 = dec[rowb + 63];
    P_xi  = *(const float4*)&xinv[bhT + t0 + c0];
#pragma unroll
    for (int r=0;r<4;r++){
      int tm1 = t0 + c0 + r - 1;
      P_xm[r] = (tm1 >= 0) ? xinv[bhT + tm1] : 0.f;
    }
  };
  auto issue_att = [&](int c){
    const bf16* pa = attn + (size_t)(bh*N_CH + c)*4096 + (wrow + l15)*64 + q*8;
    P_a[0] = *(const uint4*)pa;
    P_a[1] = *(const uint4*)(pa + 32);
  };

  // prologue
  issue_t(0);
  write_xst(0);
  issue_t(1);
  issue_main(0);
  issue_att(0);
  BAR_LGKM();

  for (int nc=0; nc<N_CH; nc++){
    const int t0 = nc*C_;
    const size_t rowb = bhT + t0;

    // ---- extract this chunk's scalars / vinit from prefetch regs ----
    float d63s = sanf(P_d63);
    float a63 = expn(d63s);
    float cdA[4] = {sanf(P_d.x), sanf(P_d.y), sanf(P_d.z), sanf(P_d.w)};
    float cxiA[4] = {sanf(P_xi.x), sanf(P_xi.y), sanf(P_xi.z), sanf(P_xi.w)};
    float sov[4], scv[4], vinitf[4];
#pragma unroll
    for (int r=0;r<4;r++){
      sov[r] = cxiA[r] * 0.08838834764831845f * expn(cdA[r]);
      scv[r] = sanf(P_xm[r]) * expn(d63s - cdA[r]);
      vinitf[r] = __bfloat162float(P_v[r]);
    }

    // ---- stage xst for chunk nc+1 (buf flips), reissue xst loads ----
    write_xst((nc+1)&1);
    issue_t(nc+2 < N_CH ? nc+2 : N_CH-1);

    // ---- phase B: accV = v - wkc@S ; accP = x@S (A from regs) ----
    f32x4 accV, accP = (f32x4){0.f,0.f,0.f,0.f};
#pragma unroll
    for (int r=0;r<4;r++) accV[r] = vinitf[r];
    __builtin_amdgcn_s_setprio(1);
#pragma unroll
    for (int ks=0; ks<4; ks++){
      bf16x8 bh_ = *(const bf16x8*)&st_hi[l15][ks*32 + q*8];
      bf16x8 bl_ = *(const bf16x8*)&st_lo[l15][ks*32 + q*8];
      uint4 uw = P_w[ks];
      uw.x ^= 0x80008000u; uw.y ^= 0x80008000u; uw.z ^= 0x80008000u; uw.w ^= 0x80008000u;
      bf16x8 a1 = u4_to_b8(uw);
      bf16x8 a2 = u4_to_b8(P_x[ks]);
      accV = __builtin_amdgcn_mfma_f32_16x16x32_bf16(a1, bh_, accV, 0,0,0);
      accV = __builtin_amdgcn_mfma_f32_16x16x32_bf16(a1, bl_, accV, 0,0,0);
      accP = __builtin_amdgcn_mfma_f32_16x16x32_bf16(a2, bh_, accP, 0,0,0);
      accP = __builtin_amdgcn_mfma_f32_16x16x32_bf16(a2, bl_, accP, 0,0,0);
    }
    __builtin_amdgcn_s_setprio(0);
    f32x4 oacc;
#pragma unroll
    for (int r=0;r<4;r++) oacc[r] = accP[r] * sov[r];
    {
      float v4[4] = {accV[0],accV[1],accV[2],accV[3]};
      *(uint2*)&vn_t[l15][c0] = pack_bf4(v4);
      float vs[4];
#pragma unroll
      for (int r=0;r<4;r++) vs[r] = accV[r] * scv[r];
      uint2 ph = pack_bf4(vs);
      float lo4[4];
      lo4[0] = vs[0] - __uint_as_float(ph.x << 16);
      lo4[1] = vs[1] - __uint_as_float(ph.x & 0xffff0000u);
      lo4[2] = vs[2] - __uint_as_float(ph.y << 16);
      lo4[3] = vs[3] - __uint_as_float(ph.y & 0xffff0000u);
      *(uint2*)&vn_sh[l15][c0] = ph;
      *(uint2*)&vn_sl[l15][c0] = pack_bf4(lo4);
    }
    // reissue main prefetches for nc+1 (loads fly across the barrier)
    issue_main(nc+1 < N_CH ? nc+1 : N_CH-1);
    BAR_LGKM();   // b2: vn ready

    // ---- phase C: o = P*sov + attn@vn, store; S = a63*S + (vn*scv)^T @ xst ----
    __builtin_amdgcn_s_setprio(1);
#pragma unroll
    for (int ks=0; ks<2; ks++){
      bf16x8 bV = *(const bf16x8*)&vn_t[l15][ks*32 + q*8];
      bf16x8 aA = u4_to_b8(P_a[ks]);
      oacc = __builtin_amdgcn_mfma_f32_16x16x32_bf16(aA, bV, oacc, 0,0,0);
    }
    __builtin_amdgcn_s_setprio(0);
    {
      bf16* po = vo + (rowb + c0)*K_ + j0 + l15;
#pragma unroll
      for (int r=0;r<4;r++) po[(size_t)r*K_] = __float2bfloat16(oacc[r]);
    }
    issue_att(nc+1 < N_CH ? nc+1 : N_CH-1);
    __builtin_amdgcn_s_setprio(1);
    {
      bf16x8 aH[2], aL[2];
#pragma unroll
      for (int ks=0; ks<2; ks++){
        aH[ks] = *(const bf16x8*)&vn_sh[l15][ks*32 + q*8];
        aL[ks] = *(const bf16x8*)&vn_sl[l15][ks*32 + q*8];
      }
#pragma unroll
      for (int sub=0; sub<2; sub++){
        f32x4 acc = accS[sub];
#pragma unroll
        for (int r=0;r<4;r++) acc[r] *= a63;
#pragma unroll
        for (int ks=0; ks<2; ks++){
          bf16x8 bX = *(const bf16x8*)&xst[nc&1][32*w + 16*sub + l15][ks*32 + q*8];
          acc = __builtin_amdgcn_mfma_f32_16x16x32_bf16(aH[ks], bX, acc, 0,0,0);
          acc = __builtin_amdgcn_mfma_f32_16x16x32_bf16(aL[ks], bX, acc, 0,0,0);
        }
        accS[sub] = acc;
#pragma unroll
        for (int r=0;r<4;r++){
          float sv = acc[r];
          bf16 hb = __float2bfloat16(sv);
          st_hi[q*4+r][32*w + 16*sub + l15] = hb;
          st_lo[q*4+r][32*w + 16*sub + l15] = __float2bfloat16(sv - __bfloat162float(hb));
        }
      }
    }
    __builtin_amdgcn_s_setprio(0);
    BAR_LGKM();   // b3: st + next xst buf ready
  }
}

extern "C" void kernel_launch(void* const* d_in, const int* in_sizes, int n_in,
                              void* d_out, int out_size, void* d_ws, size_t ws_size,
                              hipStream_t stream)
{
  const float* x       = (const float*)d_in[0];
  const float* Wv      = (const float*)d_in[1];
  const float* Wg      = (const float*)d_in[2];
  const float* Wo      = (const float*)d_in[3];
  const float* Wb      = (const float*)d_in[4];
  const float* Wa      = (const float*)d_in[5];
  const float* dt_bias = (const float*)d_in[6];
  const float* A_log   = (const float*)d_in[7];
  const float* norm_w  = (const float*)d_in[8];
  const float* conv_w  = (const float*)d_in[9];
  const float* conv_b  = (const float*)d_in[10];
  float* out = (float*)d_out;

  const size_t BTD = (size_t)B_*T_*D_;
  const size_t BHT = (size_t)B_*H_*T_;
  const size_t DD  = (size_t)D_*D_;

  // ws layout (~108.6 MB): fp32 smalls, bf16 weight copies, then big bf16 buffers
  float* beta = (float*)d_ws;          // 0.5 MiB each
  float* decr = beta + BHT;
  float* decc = decr + BHT;
  float* xinv = decc + BHT;
  bf16* Wvb = (bf16*)(xinv + BHT);     // 2 MiB each
  bf16* Wgb = Wvb + DD;
  bf16* Wob = Wgb + DD;
  bf16* xb   = Wob + DD;               // 33.5 MiB: bf16 copy of x
  bf16* vpre = xb + BTD;               // 33.5 MiB: Wv-GEMM out; later og
  bf16* wkc  = vpre + BTD;             // 33.5 MiB
  // d_out (67 MB fp32) hosts: [vchk->o bf16: BTD][attn bf16: BTD/2]
  bf16* vo   = (bf16*)d_out;
  bf16* attn = vo + BTD;

  dim3 gemm_grid(D_/128, BT_/128);   // (8, 128)
  xinv_kernel<<<BT_, 256, 0, stream>>>(x, xinv, xb);   // fused fp32->bf16 cast of x
  cast_f2b<<<(DD/4+255)/256, 256, 0, stream>>>(Wv, Wvb, DD/4);
  cast_f2b<<<(DD/4+255)/256, 256, 0, stream>>>(Wg, Wgb, DD/4);
  cast_f2b<<<(DD/4+255)/256, 256, 0, stream>>>(Wo, Wob, DD/4);
  gemm_bt_mfma<bf16,false><<<gemm_grid, 256, 0, stream>>>(xb, Wvb, vpre, BT_, D_, D_, nullptr, nullptr);
  proj_small<<<BT_/4, 256, 0, stream>>>(x, Wb, Wa, dt_bias, A_log, beta, decr);
  cumsum_dec<<<(BHT/C_)/4, 256, 0, stream>>>(decr, decc);
  chunk_prep<<<B_*H_*N_CH, 256, 0, stream>>>(xb, xinv, vpre, conv_w, conv_b,
                                             beta, decc, vo /*vchk*/, wkc, attn);
  scan_kernel<<<B_*H_*8, 256, 0, stream>>>(xb, xinv, vo, wkc, attn, decc);
  // gate GEMM with fused RMSNorm*norm_w*silu epilogue -> og (replaces norm_gate)
  gemm_bt_mfma<bf16,true><<<gemm_grid, 256, 0, stream>>>(xb, Wgb, vpre, BT_, D_, D_, vo, norm_w);
  gemm_bt_mfma<float,false><<<gemm_grid, 256, 0, stream>>>(vpre, Wob, out, BT_, D_, D_, nullptr, nullptr);
}

// Round 10
// 586.911 us; speedup vs baseline: 1.2468x; 1.0544x over previous
//
#include <hip/hip_runtime.h>
#include <hip/hip_bf16.h>
#include <math.h>

#define H_ 8
#define K_ 128
#define C_ 64
#define D_ 1024
#define T_ 4096
#define B_ 4
#define N_CH 64           // T_/C_
#define BT_ (B_*T_)

typedef __attribute__((ext_vector_type(8))) short bf16x8;
typedef __attribute__((ext_vector_type(4))) float f32x4;
typedef __hip_bfloat16 bf16;

// raw barrier: order LDS (lgkm) only; leave global loads/stores in flight (T4)
#define BAR_LGKM() do { \
  asm volatile("s_waitcnt lgkmcnt(0)" ::: "memory"); \
  __builtin_amdgcn_sched_barrier(0); \
  __builtin_amdgcn_s_barrier(); \
} while(0)

__device__ __forceinline__ float siluf(float x){ return x / (1.0f + expf(-x)); }
__device__ __forceinline__ float expn(float x){ return expf(fminf(x, 0.f)); }
__device__ __forceinline__ float sanf(float v){ return (__builtin_fabsf(v) <= 1e30f) ? v : 0.f; }

__device__ __forceinline__ void ld_bf4(const bf16* p, float* o){
  uint2 u = *(const uint2*)p;
  o[0]=__uint_as_float(u.x<<16); o[1]=__uint_as_float(u.x&0xffff0000u);
  o[2]=__uint_as_float(u.y<<16); o[3]=__uint_as_float(u.y&0xffff0000u);
}
__device__ __forceinline__ void ld_bf4s(const bf16* p, float* o){
  ld_bf4(p, o);
#pragma unroll
  for (int e=0;e<4;e++) o[e] = sanf(o[e]);
}
__device__ __forceinline__ unsigned short f2bfu(float f){
  bf16 h = __float2bfloat16(f);
  return *reinterpret_cast<unsigned short*>(&h);
}
__device__ __forceinline__ uint2 pack_bf4(const float* v){
  uint2 r;
  r.x = (unsigned)f2bfu(v[0]) | ((unsigned)f2bfu(v[1])<<16);
  r.y = (unsigned)f2bfu(v[2]) | ((unsigned)f2bfu(v[3])<<16);
  return r;
}
__device__ __forceinline__ bf16x8 u4_to_b8(uint4 u){
  union { uint4 u; bf16x8 b; } cv; cv.u = u; return cv.b;
}

// ---- fully-unrolled forward substitution (template-const indices: rule #20) ----
template<int I> __device__ __forceinline__ void fsub_step(float* v, const float (*sa)[64]){
  const float* ar = sa[I];
  float s0=0.f,s1=0.f,s2=0.f,s3=0.f;
  constexpr int I4 = I & ~3;
#pragma unroll
  for (int j=0;j<I4;j+=4){
    float4 a4 = *(const float4*)&ar[j];
    s0 += a4.x*v[j+0]; s1 += a4.y*v[j+1]; s2 += a4.z*v[j+2]; s3 += a4.w*v[j+3];
  }
#pragma unroll
  for (int j=I4;j<I;j++) s0 += ar[j]*v[j];
  v[I] += (s0+s2)+(s1+s3);
}
template<int I> __device__ __forceinline__ void fsub_all(float* v, const float (*sa)[64]){
  if constexpr (I >= 1){
    fsub_all<I-1>(v, sa);
    fsub_step<I>(v, sa);
  }
}

// ---------------- fp32 -> bf16 cast ----------------
__global__ __launch_bounds__(256) void cast_f2b(
    const float* __restrict__ src, bf16* __restrict__ dst, int n4)
{
  int i = blockIdx.x*256 + threadIdx.x;
  if (i >= n4) return;
  float4 v = *(const float4*)&src[(size_t)i*4];
  float a[4] = {v.x, v.y, v.z, v.w};
  *(uint2*)&dst[(size_t)i*4] = pack_bf4(a);
}

// ---------------- MFMA GEMM: Y[M,N] = X[M,K](bf16) @ W[N,K](bf16)^T ----------------
// global_load_lds width-16 staging, linear LDS dest, both-sides XOR swizzle
// (rule #21). FUSE_NG: fused per-head RMSNorm * norm_w * silu(gate) epilogue
// (gate GEMM; grid.x == H_, each block covers exactly one head's 128 cols).
template<typename OUT_T, bool FUSE_NG>
__global__ __launch_bounds__(256) void gemm_bt_mfma(
    const bf16* __restrict__ X, const bf16* __restrict__ W,
    OUT_T* __restrict__ Y, int M, int N, int K,
    const bf16* __restrict__ o_in, const float* __restrict__ norm_w)
{
  __shared__ __align__(16) bf16 As[128*64];
  __shared__ __align__(16) bf16 Bs[128*64];
  const int tid = threadIdx.x;
  const int wv = tid >> 6;
  const int lane = tid & 63;
  const int row0 = blockIdx.y*128, col0 = blockIdx.x*128;
  const int mw = (wv&1)*64, nw = (wv>>1)*64;
  const int q = lane >> 4;
  const int l15 = lane & 15;
  const int swr = l15 & 7;
  f32x4 acc[4][4];
#pragma unroll
  for (int mi=0;mi<4;mi++)
#pragma unroll
    for (int ni=0;ni<4;ni++) acc[mi][ni] = (f32x4){0.f,0.f,0.f,0.f};

  const int sr8 = lane >> 3;
  const int scs = ((lane & 7) ^ sr8) * 8;
  for (int k0=0;k0<K;k0+=64){
#pragma unroll
    for (int i=0;i<4;i++){
      __builtin_amdgcn_global_load_lds(
          (const void*)&X[(size_t)(row0 + i*32 + wv*8 + sr8)*K + k0 + scs],
          (void*)&As[i*2048 + wv*512], 16, 0, 0);
      __builtin_amdgcn_global_load_lds(
          (const void*)&W[(size_t)(col0 + i*32 + wv*8 + sr8)*K + k0 + scs],
          (void*)&Bs[i*2048 + wv*512], 16, 0, 0);
    }
    __syncthreads();
#pragma unroll
    for (int ks=0; ks<64; ks+=32){
      bf16x8 af[4], bfr[4];
#pragma unroll
      for (int i=0;i<4;i++){
        const int cc = (((ks>>3) + q) ^ swr) * 8;
        af[i]  = *(const bf16x8*)&As[(mw + i*16 + l15)*64 + cc];
        bfr[i] = *(const bf16x8*)&Bs[(nw + i*16 + l15)*64 + cc];
      }
#pragma unroll
      for (int mi=0;mi<4;mi++)
#pragma unroll
        for (int ni=0;ni<4;ni++)
          acc[mi][ni] = __builtin_amdgcn_mfma_f32_16x16x32_bf16(af[mi], bfr[ni], acc[mi][ni], 0,0,0);
    }
    __syncthreads();
  }

  if constexpr (FUSE_NG){
    // ---- fused RMSNorm(o)*norm_w*silu(gate) -> og ----
    float* s_red = (float*)As;          // 256 floats; As dead after last sync
    const int hh = blockIdx.x;          // head (grid.x == H_)
    const int nwh = nw >> 6;            // 0 or 1
#pragma unroll
    for (int mi=0;mi<4;mi++){
#pragma unroll
      for (int reg=0;reg<4;reg++){
        int row = row0 + mw + mi*16 + q*4 + reg;
        int b = row >> 12, t = row & (T_-1);
        const bf16* orow = o_in + ((size_t)(b*H_+hh)*T_ + t)*K_;
        float ps = 0.f;
#pragma unroll
        for (int ni=0;ni<4;ni++){
          float ov = sanf(__bfloat162float(orow[nw + ni*16 + l15]));
          ps += ov*ov;
        }
        ps += __shfl_xor(ps,1,64); ps += __shfl_xor(ps,2,64);
        ps += __shfl_xor(ps,4,64); ps += __shfl_xor(ps,8,64);
        if (l15 == 0) s_red[nwh*128 + mw + mi*16 + q*4 + reg] = ps;
      }
    }
    __syncthreads();
#pragma unroll
    for (int mi=0;mi<4;mi++){
#pragma unroll
      for (int reg=0;reg<4;reg++){
        int lr = mw + mi*16 + q*4 + reg;
        float ssum = s_red[lr] + s_red[128 + lr];
        float rr = rsqrtf(ssum*(1.f/128.f) + 1e-5f);
        int row = row0 + lr;
        int b = row >> 12, t = row & (T_-1);
        const bf16* orow = o_in + ((size_t)(b*H_+hh)*T_ + t)*K_;
#pragma unroll
        for (int ni=0;ni<4;ni++){
          int k = nw + ni*16 + l15;
          float ov = sanf(__bfloat162float(orow[k]));
          float res = ov * rr * norm_w[k] * siluf(acc[mi][ni][reg]);
          Y[(size_t)row*N + col0 + k] = (OUT_T)__float2bfloat16(res);
        }
      }
    }
  } else {
#pragma unroll
    for (int mi=0;mi<4;mi++){
#pragma unroll
      for (int reg=0;reg<4;reg++){
        int row = row0 + mw + mi*16 + q*4 + reg;
#pragma unroll
        for (int ni=0;ni<4;ni++){
          int col = col0 + nw + ni*16 + l15;
          if constexpr (sizeof(OUT_T) == 2)
            Y[(size_t)row*N + col] = (OUT_T)__float2bfloat16(acc[mi][ni][reg]);
          else
            Y[(size_t)row*N + col] = (OUT_T)acc[mi][ni][reg];
        }
      }
    }
  }
}

// ------------- beta = sigmoid(x@Wb^T), decay = -exp(A_log)*softplus(x@Wa^T+dt_bias) -------------
__global__ __launch_bounds__(256) void proj_small(
    const float* __restrict__ x, const float* __restrict__ Wb, const float* __restrict__ Wa,
    const float* __restrict__ dt_bias, const float* __restrict__ A_log,
    float* __restrict__ beta_out, float* __restrict__ dec_out)
{
  const int w = threadIdx.x >> 6;
  const int lane = threadIdx.x & 63;
  const int bt = blockIdx.x*4 + w;
  const int b = bt >> 12, t = bt & (T_-1);
  const float* xr = x + (size_t)bt*D_;
  float xv[16];
#pragma unroll
  for (int p=0;p<4;p++){
    float4 v = *(const float4*)&xr[lane*16 + p*4];
    xv[p*4+0]=v.x; xv[p*4+1]=v.y; xv[p*4+2]=v.z; xv[p*4+3]=v.w;
  }
  float accb[H_], acca[H_];
#pragma unroll
  for (int h=0;h<H_;h++){
    float sb=0.f, sa=0.f;
#pragma unroll
    for (int p=0;p<4;p++){
      float4 wb = *(const float4*)&Wb[(size_t)h*D_ + lane*16 + p*4];
      float4 wa = *(const float4*)&Wa[(size_t)h*D_ + lane*16 + p*4];
      sb += xv[p*4+0]*wb.x + xv[p*4+1]*wb.y + xv[p*4+2]*wb.z + xv[p*4+3]*wb.w;
      sa += xv[p*4+0]*wa.x + xv[p*4+1]*wa.y + xv[p*4+2]*wa.z + xv[p*4+3]*wa.w;
    }
    accb[h]=sb; acca[h]=sa;
  }
#pragma unroll
  for (int h=0;h<H_;h++){
#pragma unroll
    for (int m=1;m<64;m<<=1){
      accb[h] += __shfl_xor(accb[h], m, 64);
      acca[h] += __shfl_xor(acca[h], m, 64);
    }
  }
  if (lane < H_) {
    int h = lane;
    beta_out[(size_t)(b*H_+h)*T_ + t] = 1.f/(1.f+expf(-accb[h]));
  } else if (lane < 2*H_) {
    int h = lane - H_;
    float z = acca[h] + dt_bias[h];
    float sp = fmaxf(z,0.f) + log1pf(expf(-fabsf(z)));
    dec_out[(size_t)(b*H_+h)*T_ + t] = -expf(A_log[h]) * sp;
  }
}

// ------------- xinv + fused fp32->bf16 cast of x -------------
__global__ __launch_bounds__(256) void xinv_kernel(
    const float* __restrict__ x, float* __restrict__ xinv, bf16* __restrict__ xb)
{
  const int bt = blockIdx.x;
  const int b = bt >> 12, t = bt & (T_-1);
  const int tid = threadIdx.x;
  float4 xv = *(const float4*)&x[(size_t)bt*D_ + tid*4];
  float a[4] = {xv.x, xv.y, xv.z, xv.w};
  *(uint2*)&xb[(size_t)bt*D_ + tid*4] = pack_bf4(a);
  float ss = xv.x*xv.x + xv.y*xv.y + xv.z*xv.z + xv.w*xv.w;
#pragma unroll
  for (int m=1;m<32;m<<=1) ss += __shfl_xor(ss, m, 32);
  const int h = tid >> 5;
  if ((tid & 31) == 0)
    xinv[(size_t)(b*H_+h)*T_ + t] = rsqrtf(ss + 1e-6f);
}

// ------------- per-chunk cumsum of decay (fp32) -------------
__global__ __launch_bounds__(256) void cumsum_dec(
    const float* __restrict__ dec_raw, float* __restrict__ dec_cum)
{
  int g = blockIdx.x*4 + (threadIdx.x>>6);
  int lane = threadIdx.x & 63;
  float v = sanf(dec_raw[(size_t)g*C_ + lane]);
#pragma unroll
  for (int off=1; off<64; off<<=1){
    float u = __shfl_up(v, off, 64);
    if (lane >= off) v += u;
  }
  dec_cum[(size_t)g*C_ + lane] = v;
}

// ------------- per-chunk prep, MFMA version -------------
__global__ __launch_bounds__(256) void chunk_prep(
    const bf16* __restrict__ xb, const float* __restrict__ xinv,
    const bf16* __restrict__ vpre, const float* __restrict__ cw, const float* __restrict__ cb,
    const float* __restrict__ beta, const float* __restrict__ dec,
    bf16* __restrict__ vchk, bf16* __restrict__ wkc, bf16* __restrict__ attn)
{
  __shared__ __align__(16) bf16 s_x[65][136];    // s_x[r] = x[t0+r-1] raw bf16
  __shared__ __align__(16) float s_a[64][64];    // A matrix (fp32, strict lower)
  __shared__ float s_dec[64], s_beta[64], s_invsh[64], s_negbi[64], s_rsc[64], s_sc2[64];

  const int tid = threadIdx.x;
  const int chunk = blockIdx.x;
  const int bh = chunk >> 6;
  const int nc = chunk & 63;
  const int b = bh >> 3, h = bh & 7;
  const int t0 = nc * C_;
  const size_t xrow = (size_t)b*T_;
  const size_t rowb = (size_t)bh*T_ + t0;
  const size_t kobase = rowb * K_;
  const int w = tid >> 6;
  const int lane = tid & 63;
  const int l15 = lane & 15;
  const int q = lane >> 4;

  for (int idx = tid; idx < 65*16; idx += 256){
    int r = idx >> 4;
    int seg = (idx & 15) * 8;
    int t = t0 + r - 1;
    int tr = t < 0 ? 0 : t;
    *(uint4*)&s_x[r][seg] = *(const uint4*)&xb[(xrow + tr)*D_ + h*K_ + seg];
  }
  if (tid < C_){
    int c = tid;
    float dv  = sanf(dec[rowb + c]);
    float bet = sanf(beta[rowb + c]);
    float invc = sanf(xinv[rowb + c]);
    int tm1 = t0 + c - 1;
    float ivs = (tm1 >= 0) ? sanf(xinv[(size_t)bh*T_ + tm1]) : 0.f;
    s_dec[c] = dv;
    s_beta[c] = bet;
    s_invsh[c] = ivs;
    s_negbi[c] = -bet * ivs;
    s_rsc[c] = invc * 0.08838834764831845f;
    s_sc2[c] = ivs * bet * expn(dv);
  }
  __syncthreads();

  bf16x8 aG[4], aT[4];
#pragma unroll
  for (int ks=0; ks<4; ks++){
    aG[ks] = *(const bf16x8*)&s_x[16*w + l15][ks*32 + q*8];
    aT[ks] = *(const bf16x8*)&s_x[16*w + l15 + 1][ks*32 + q*8];
  }
  f32x4 accG[4], accT[4];
#pragma unroll
  for (int J=0;J<4;J++){ accG[J]=(f32x4){0.f,0.f,0.f,0.f}; accT[J]=(f32x4){0.f,0.f,0.f,0.f}; }
#pragma unroll
  for (int J=0;J<4;J++){
    if (J <= w){
#pragma unroll
      for (int ks=0; ks<4; ks++){
        bf16x8 bfrag = *(const bf16x8*)&s_x[16*J + l15][ks*32 + q*8];
        accG[J] = __builtin_amdgcn_mfma_f32_16x16x32_bf16(aG[ks], bfrag, accG[J], 0,0,0);
        accT[J] = __builtin_amdgcn_mfma_f32_16x16x32_bf16(aT[ks], bfrag, accT[J], 0,0,0);
      }
    }
  }
  {
    const int i0 = 16*w + q*4;
#pragma unroll
    for (int J=0;J<4;J++){
      const int j = 16*J + l15;
#pragma unroll
      for (int reg=0;reg<4;reg++){
        const int i = i0 + reg;
        if (j < i)
          s_a[i][j] = s_negbi[i] * s_invsh[j] * expn(s_dec[i]-s_dec[j]) * accG[J][reg];
        float val = 0.f;
        if (j <= i)
          val = s_rsc[i] * s_invsh[j] * expn(s_dec[i]-s_dec[j]) * accT[J][reg];
        attn[(size_t)chunk*4096 + i*64 + j] = __float2bfloat16(val);
      }
    }
  }

  float v[64];
  if (tid < 128){
    const int col = tid;
    float4 cwv = *(const float4*)&cw[(h*K_+col)*4];
    const float cbv = cb[h*K_+col];
    const bf16* vp = vpre + (xrow + t0)*D_ + h*K_ + col;
    float win0, win1, win2;
    { int t = t0-3; win0 = (t>=0)? sanf(__bfloat162float(vpre[(xrow+t)*D_+h*K_+col])) : 0.f; }
    { int t = t0-2; win1 = (t>=0)? sanf(__bfloat162float(vpre[(xrow+t)*D_+h*K_+col])) : 0.f; }
    { int t = t0-1; win2 = (t>=0)? sanf(__bfloat162float(vpre[(xrow+t)*D_+h*K_+col])) : 0.f; }
#pragma unroll
    for (int c8=0; c8<8; c8++){
      float nv[8];
#pragma unroll
      for (int u=0;u<8;u++) nv[u] = sanf(__bfloat162float(vp[(size_t)(c8*8+u)*D_]));
#pragma unroll
      for (int u=0;u<8;u++){
        const int c = c8*8+u;
        float a = cbv + cwv.x*win0 + cwv.y*win1 + cwv.z*win2 + cwv.w*nv[u];
        v[c] = siluf(a) * s_beta[c];
        win0=win1; win1=win2; win2=nv[u];
      }
    }
  } else {
    const int col = tid - 128;
#pragma unroll
    for (int c=0;c<64;c++)
      v[c] = __bfloat162float(s_x[c][col]) * s_sc2[c];
  }
  __syncthreads();   // s_a complete

  fsub_all<63>(v, s_a);

  {
    const int col = tid & 127;
    bf16* dst = (tid < 128 ? vchk : wkc) + kobase + col;
#pragma unroll
    for (int c=0;c<64;c++)
      dst[(size_t)c*K_] = __float2bfloat16(v[c]);
  }
}

// ------------- sequential chunk scan: LDS-diet + 8-wave role split -------------
// Grid 256 (bh = bid&31 keeps the 8 column-group siblings on one XCD's L2),
// 512 threads. Waves 0-3 (state waves) own the serial path:
// accV = v - wkc@S -> vn -> S-update -> st. Waves 4-7 (output waves) do all
// off-path work: accP = x@S, o = P*sov + attn@vn + store, xst transpose
// staging, attn prefetch. All global addresses advance by constant strides
// (incremental pointers) -- no per-chunk 64-bit address recomputation.
// 2 lgkm-only barriers per chunk; LDS 52.5 KB.
__global__ __launch_bounds__(512) void scan_kernel(
    const bf16* __restrict__ xb, const float* __restrict__ xinv, bf16* vo,
    const bf16* __restrict__ wkc, const bf16* __restrict__ attn,
    const float* __restrict__ dec)
{
  __shared__ __align__(16) bf16 xst[2][128][72];
  __shared__ __align__(16) bf16 st_hi[16][136];
  __shared__ __align__(16) bf16 st_lo[16][136];
  __shared__ __align__(16) bf16 vn_t [16][72];
  __shared__ __align__(16) bf16 vn_sh[16][72];
  __shared__ __align__(16) bf16 vn_sl[16][72];

  const int tid = threadIdx.x;
  const int bh = blockIdx.x & 31;
  const int g  = blockIdx.x >> 5;
  const int b = bh >> 3, h = bh & 7;
  const int j0 = g*16;
  const int w  = tid >> 6;
  const int wm = w & 3;
  const int lane = tid & 63;
  const int l15 = lane & 15;
  const int q = lane >> 4;
  const int wrow = 16*wm;
  const int c0 = wrow + q*4;          // this thread's 4 chunk-rows
  const size_t xrow = (size_t)b*T_;
  const size_t bhT = (size_t)bh*T_;

  for (int e=tid; e<16*136; e+=512){
    ((unsigned short*)&st_hi[0][0])[e] = 0;
    ((unsigned short*)&st_lo[0][0])[e] = 0;
  }

  if (w < 4){
    // ================= STATE WAVES: accV + S-update =================
    f32x4 accS[2];
    accS[0] = (f32x4){0.f,0.f,0.f,0.f};
    accS[1] = (f32x4){0.f,0.f,0.f,0.f};

    const bf16*  pw   = wkc + (bhT + wrow + l15)*K_ + q*8;
    const bf16*  pv   = vo  + (bhT + c0)*K_ + j0 + l15;
    const float* pd   = dec + bhT + c0;
    const float* pd63 = dec + bhT + 63;
    const float* pxm  = xinv + bhT + c0;

    uint4 P_w[4]; bf16 P_v[4]; float4 P_d; float P_d63, P_xm[4];
#pragma unroll
    for (int ks=0; ks<4; ks++) P_w[ks] = *(const uint4*)(pw + ks*32);
#pragma unroll
    for (int r=0;r<4;r++) P_v[r] = pv[(size_t)r*K_];
    P_d = *(const float4*)pd;
    P_d63 = *pd63;
#pragma unroll
    for (int r=0;r<4;r++){
      int tm1 = c0 + r - 1;
      P_xm[r] = (tm1 >= 0) ? xinv[bhT + tm1] : 0.f;
    }
    BAR_LGKM();   // prologue

    for (int nc=0; nc<N_CH; nc++){
      float d63s = sanf(P_d63);
      float a63 = expn(d63s);
      float cd[4] = {sanf(P_d.x), sanf(P_d.y), sanf(P_d.z), sanf(P_d.w)};
      float scv[4], vinitf[4];
#pragma unroll
      for (int r=0;r<4;r++){
        scv[r] = sanf(P_xm[r]) * expn(d63s - cd[r]);
        vinitf[r] = __bfloat162float(P_v[r]);
      }

      // ---- phase B: accV = v - wkc@S ----
      f32x4 accV;
#pragma unroll
      for (int r=0;r<4;r++) accV[r] = vinitf[r];
      __builtin_amdgcn_s_setprio(1);
#pragma unroll
      for (int ks=0; ks<4; ks++){
        bf16x8 bh_ = *(const bf16x8*)&st_hi[l15][ks*32 + q*8];
        bf16x8 bl_ = *(const bf16x8*)&st_lo[l15][ks*32 + q*8];
        uint4 uw = P_w[ks];
        uw.x ^= 0x80008000u; uw.y ^= 0x80008000u; uw.z ^= 0x80008000u; uw.w ^= 0x80008000u;
        bf16x8 a1 = u4_to_b8(uw);
        accV = __builtin_amdgcn_mfma_f32_16x16x32_bf16(a1, bh_, accV, 0,0,0);
        accV = __builtin_amdgcn_mfma_f32_16x16x32_bf16(a1, bl_, accV, 0,0,0);
      }
      __builtin_amdgcn_s_setprio(0);
      {
        float v4[4] = {accV[0],accV[1],accV[2],accV[3]};
        *(uint2*)&vn_t[l15][c0] = pack_bf4(v4);
        float vs[4];
#pragma unroll
        for (int r=0;r<4;r++) vs[r] = accV[r] * scv[r];
        uint2 ph = pack_bf4(vs);
        float lo4[4];
        lo4[0] = vs[0] - __uint_as_float(ph.x << 16);
        lo4[1] = vs[1] - __uint_as_float(ph.x & 0xffff0000u);
        lo4[2] = vs[2] - __uint_as_float(ph.y << 16);
        lo4[3] = vs[3] - __uint_as_float(ph.y & 0xffff0000u);
        *(uint2*)&vn_sh[l15][c0] = ph;
        *(uint2*)&vn_sl[l15][c0] = pack_bf4(lo4);
      }
      // ---- prefetch next chunk (loads fly across barriers) ----
      if (nc+1 < N_CH){ pw += (size_t)C_*K_; pv += (size_t)C_*K_; pd += C_; pd63 += C_; pxm += C_; }
#pragma unroll
      for (int ks=0; ks<4; ks++) P_w[ks] = *(const uint4*)(pw + ks*32);
#pragma unroll
      for (int r=0;r<4;r++) P_v[r] = pv[(size_t)r*K_];
      P_d = *(const float4*)pd;
      P_d63 = *pd63;
#pragma unroll
      for (int r=0;r<4;r++) P_xm[r] = pxm[r-1];   // t index >= 63, never clamps
      BAR_LGKM();   // b2: vn ready

      // ---- phase C: S = a63*S + (vn*scv)^T @ xst ----
      __builtin_amdgcn_s_setprio(1);
      bf16x8 aH[2], aL[2];
#pragma unroll
      for (int ks=0; ks<2; ks++){
        aH[ks] = *(const bf16x8*)&vn_sh[l15][ks*32 + q*8];
        aL[ks] = *(const bf16x8*)&vn_sl[l15][ks*32 + q*8];
      }
#pragma unroll
      for (int sub=0; sub<2; sub++){
        f32x4 acc = accS[sub];
#pragma unroll
        for (int r=0;r<4;r++) acc[r] *= a63;
#pragma unroll
        for (int ks=0; ks<2; ks++){
          bf16x8 bX = *(const bf16x8*)&xst[nc&1][32*wm + 16*sub + l15][ks*32 + q*8];
          acc = __builtin_amdgcn_mfma_f32_16x16x32_bf16(aH[ks], bX, acc, 0,0,0);
          acc = __builtin_amdgcn_mfma_f32_16x16x32_bf16(aL[ks], bX, acc, 0,0,0);
        }
        accS[sub] = acc;
#pragma unroll
        for (int r=0;r<4;r++){
          float sv = acc[r];
          bf16 hb = __float2bfloat16(sv);
          st_hi[q*4+r][32*wm + 16*sub + l15] = hb;
          st_lo[q*4+r][32*wm + 16*sub + l15] = __float2bfloat16(sv - __bfloat162float(hb));
        }
      }
      __builtin_amdgcn_s_setprio(0);
      BAR_LGKM();   // b3: st + next xst buf ready
    }
  } else {
    // ================= OUTPUT WAVES: accP + o + xst staging =================
    const int tp = tid - 256;
    const int xc0 = (tp & 31)*2;
    const int xkb = (tp >> 5)*16;

    uint4 T_r[4];
    uint4 P_x[4], P_a[2];
    float4 P_dP, P_xi;

    // prologue: T_r <- chunk 0 (clamped), write buf0; T_r <- chunk 1
    {
      int t1 = xc0 - 1;
      const bf16* p1 = xb + (xrow + (t1<0?0:t1))*D_ + h*K_ + xkb;
      const bf16* p2 = xb + (xrow + xc0)*D_ + h*K_ + xkb;
      T_r[0]=*(const uint4*)p1; T_r[1]=*(const uint4*)(p1+8);
      T_r[2]=*(const uint4*)p2; T_r[3]=*(const uint4*)(p2+8);
    }
    {
      unsigned r1[8]={T_r[0].x,T_r[0].y,T_r[0].z,T_r[0].w,T_r[1].x,T_r[1].y,T_r[1].z,T_r[1].w};
      unsigned r2[8]={T_r[2].x,T_r[2].y,T_r[2].z,T_r[2].w,T_r[3].x,T_r[3].y,T_r[3].z,T_r[3].w};
#pragma unroll
      for (int i2=0;i2<8;i2++){
        *(unsigned*)&xst[0][xkb + 2*i2][xc0]     = (r1[i2] & 0xffffu) | (r2[i2] << 16);
        *(unsigned*)&xst[0][xkb + 2*i2 + 1][xc0] = (r1[i2] >> 16) | (r2[i2] & 0xffff0000u);
      }
    }
    {
      const bf16* p1 = xb + (xrow + C_ + xc0 - 1)*D_ + h*K_ + xkb;
      const bf16* p2 = xb + (xrow + C_ + xc0)*D_ + h*K_ + xkb;
      T_r[0]=*(const uint4*)p1; T_r[1]=*(const uint4*)(p1+8);
      T_r[2]=*(const uint4*)p2; T_r[3]=*(const uint4*)(p2+8);
    }
    const bf16* pt1 = xb + (xrow + 2*C_ + xc0 - 1)*D_ + h*K_ + xkb;
    const bf16* pt2 = xb + (xrow + 2*C_ + xc0)*D_ + h*K_ + xkb;

    const bf16*  px  = xb + (xrow + wrow + l15)*D_ + h*K_ + q*8;
    const bf16*  pa  = attn + (size_t)(bh*N_CH)*4096 + (wrow + l15)*64 + q*8;
    const float* pdP = dec + bhT + c0;
    const float* pxi = xinv + bhT + c0;
    bf16*        pvo = vo + (bhT + c0)*K_ + j0 + l15;

#pragma unroll
    for (int ks=0; ks<4; ks++) P_x[ks] = *(const uint4*)(px + ks*32);
    P_a[0] = *(const uint4*)pa; P_a[1] = *(const uint4*)(pa + 32);
    P_dP = *(const float4*)pdP;
    P_xi = *(const float4*)pxi;
    BAR_LGKM();   // prologue

    for (int nc=0; nc<N_CH; nc++){
      float cd[4]  = {sanf(P_dP.x), sanf(P_dP.y), sanf(P_dP.z), sanf(P_dP.w)};
      float cxi[4] = {sanf(P_xi.x), sanf(P_xi.y), sanf(P_xi.z), sanf(P_xi.w)};
      float sov[4];
#pragma unroll
      for (int r=0;r<4;r++) sov[r] = cxi[r] * 0.08838834764831845f * expn(cd[r]);

      // ---- stage xst[(nc+1)&1] from T_r (chunk nc+1); reissue for nc+2 ----
      {
        unsigned r1[8]={T_r[0].x,T_r[0].y,T_r[0].z,T_r[0].w,T_r[1].x,T_r[1].y,T_r[1].z,T_r[1].w};
        unsigned r2[8]={T_r[2].x,T_r[2].y,T_r[2].z,T_r[2].w,T_r[3].x,T_r[3].y,T_r[3].z,T_r[3].w};
        const int buf = (nc+1)&1;
#pragma unroll
        for (int i2=0;i2<8;i2++){
          *(unsigned*)&xst[buf][xkb + 2*i2][xc0]     = (r1[i2] & 0xffffu) | (r2[i2] << 16);
          *(unsigned*)&xst[buf][xkb + 2*i2 + 1][xc0] = (r1[i2] >> 16) | (r2[i2] & 0xffff0000u);
        }
      }
      if (nc+2 < N_CH){
        T_r[0]=*(const uint4*)pt1; T_r[1]=*(const uint4*)(pt1+8);
        T_r[2]=*(const uint4*)pt2; T_r[3]=*(const uint4*)(pt2+8);
        pt1 += (size_t)C_*D_; pt2 += (size_t)C_*D_;
      }

      // ---- phase B: accP = x@S ----
      f32x4 accP = (f32x4){0.f,0.f,0.f,0.f};
      __builtin_amdgcn_s_setprio(1);
#pragma unroll
      for (int ks=0; ks<4; ks++){
        bf16x8 bh_ = *(const bf16x8*)&st_hi[l15][ks*32 + q*8];
        bf16x8 bl_ = *(const bf16x8*)&st_lo[l15][ks*32 + q*8];
        bf16x8 a2 = u4_to_b8(P_x[ks]);
        accP = __builtin_amdgcn_mfma_f32_16x16x32_bf16(a2, bh_, accP, 0,0,0);
        accP = __builtin_amdgcn_mfma_f32_16x16x32_bf16(a2, bl_, accP, 0,0,0);
      }
      __builtin_amdgcn_s_setprio(0);
      f32x4 oacc;
#pragma unroll
      for (int r=0;r<4;r++) oacc[r] = accP[r] * sov[r];
      // prefetch next chunk's x / scalars
      if (nc+1 < N_CH){ px += (size_t)C_*D_; pdP += C_; pxi += C_; }
#pragma unroll
      for (int ks=0; ks<4; ks++) P_x[ks] = *(const uint4*)(px + ks*32);
      P_dP = *(const float4*)pdP;
      P_xi = *(const float4*)pxi;
      BAR_LGKM();   // b2: vn_t ready

      // ---- phase C: oacc += attn@vn; store o ----
      __builtin_amdgcn_s_setprio(1);
#pragma unroll
      for (int ks=0; ks<2; ks++){
        bf16x8 bV = *(const bf16x8*)&vn_t[l15][ks*32 + q*8];
        bf16x8 aA = u4_to_b8(P_a[ks]);
        oacc = __builtin_amdgcn_mfma_f32_16x16x32_bf16(aA, bV, oacc, 0,0,0);
      }
      __builtin_amdgcn_s_setprio(0);
#pragma unroll
      for (int r=0;r<4;r++) pvo[(size_t)r*K_] = __float2bfloat16(oacc[r]);
      pvo += (size_t)C_*K_;
      if (nc+1 < N_CH){ pa += 4096; }
      P_a[0] = *(const uint4*)pa; P_a[1] = *(const uint4*)(pa + 32);
      BAR_LGKM();   // b3
    }
  }
}

extern "C" void kernel_launch(void* const* d_in, const int* in_sizes, int n_in,
                              void* d_out, int out_size, void* d_ws, size_t ws_size,
                              hipStream_t stream)
{
  const float* x       = (const float*)d_in[0];
  const float* Wv      = (const float*)d_in[1];
  const float* Wg      = (const float*)d_in[2];
  const float* Wo      = (const float*)d_in[3];
  const float* Wb      = (const float*)d_in[4];
  const float* Wa      = (const float*)d_in[5];
  const float* dt_bias = (const float*)d_in[6];
  const float* A_log   = (const float*)d_in[7];
  const float* norm_w  = (const float*)d_in[8];
  const float* conv_w  = (const float*)d_in[9];
  const float* conv_b  = (const float*)d_in[10];
  float* out = (float*)d_out;

  const size_t BTD = (size_t)B_*T_*D_;
  const size_t BHT = (size_t)B_*H_*T_;
  const size_t DD  = (size_t)D_*D_;

  // ws layout (~108.6 MB): fp32 smalls, bf16 weight copies, then big bf16 buffers
  float* beta = (float*)d_ws;          // 0.5 MiB each
  float* decr = beta + BHT;
  float* decc = decr + BHT;
  float* xinv = decc + BHT;
  bf16* Wvb = (bf16*)(xinv + BHT);     // 2 MiB each
  bf16* Wgb = Wvb + DD;
  bf16* Wob = Wgb + DD;
  bf16* xb   = Wob + DD;               // 33.5 MiB: bf16 copy of x
  bf16* vpre = xb + BTD;               // 33.5 MiB: Wv-GEMM out; later og
  bf16* wkc  = vpre + BTD;             // 33.5 MiB
  // d_out (67 MB fp32) hosts: [vchk->o bf16: BTD][attn bf16: BTD/2]
  bf16* vo   = (bf16*)d_out;
  bf16* attn = vo + BTD;

  dim3 gemm_grid(D_/128, BT_/128);   // (8, 128)
  xinv_kernel<<<BT_, 256, 0, stream>>>(x, xinv, xb);   // fused fp32->bf16 cast of x
  cast_f2b<<<(DD/4+255)/256, 256, 0, stream>>>(Wv, Wvb, DD/4);
  cast_f2b<<<(DD/4+255)/256, 256, 0, stream>>>(Wg, Wgb, DD/4);
  cast_f2b<<<(DD/4+255)/256, 256, 0, stream>>>(Wo, Wob, DD/4);
  gemm_bt_mfma<bf16,false><<<gemm_grid, 256, 0, stream>>>(xb, Wvb, vpre, BT_, D_, D_, nullptr, nullptr);
  proj_small<<<BT_/4, 256, 0, stream>>>(x, Wb, Wa, dt_bias, A_log, beta, decr);
  cumsum_dec<<<(BHT/C_)/4, 256, 0, stream>>>(decr, decc);
  chunk_prep<<<B_*H_*N_CH, 256, 0, stream>>>(xb, xinv, vpre, conv_w, conv_b,
                                             beta, decc, vo /*vchk*/, wkc, attn);
  scan_kernel<<<B_*H_*8, 512, 0, stream>>>(xb, xinv, vo, wkc, attn, decc);
  // gate GEMM with fused RMSNorm*norm_w*silu epilogue -> og (replaces norm_gate)
  gemm_bt_mfma<bf16,true><<<gemm_grid, 256, 0, stream>>>(xb, Wgb, vpre, BT_, D_, D_, vo, norm_w);
  gemm_bt_mfma<float,false><<<gemm_grid, 256, 0, stream>>>(vpre, Wob, out, BT_, D_, D_, nullptr, nullptr);
}

// Round 11
// 553.814 us; speedup vs baseline: 1.3213x; 1.0598x over previous
//
#include <hip/hip_runtime.h>
#include <hip/hip_bf16.h>
#include <math.h>

#define H_ 8
#define K_ 128
#define C_ 64
#define D_ 1024
#define T_ 4096
#define B_ 4
#define N_CH 64           // T_/C_
#define BT_ (B_*T_)

typedef __attribute__((ext_vector_type(8))) short bf16x8;
typedef __attribute__((ext_vector_type(4))) float f32x4;
typedef __hip_bfloat16 bf16;

// raw barrier: order LDS (lgkm) only; leave global loads/stores in flight (T4)
#define BAR_LGKM() do { \
  asm volatile("s_waitcnt lgkmcnt(0)" ::: "memory"); \
  __builtin_amdgcn_sched_barrier(0); \
  __builtin_amdgcn_s_barrier(); \
} while(0)

__device__ __forceinline__ float siluf(float x){ return x / (1.0f + expf(-x)); }
__device__ __forceinline__ float expn(float x){ return expf(fminf(x, 0.f)); }
__device__ __forceinline__ float sanf(float v){ return (__builtin_fabsf(v) <= 1e30f) ? v : 0.f; }

__device__ __forceinline__ void ld_bf4(const bf16* p, float* o){
  uint2 u = *(const uint2*)p;
  o[0]=__uint_as_float(u.x<<16); o[1]=__uint_as_float(u.x&0xffff0000u);
  o[2]=__uint_as_float(u.y<<16); o[3]=__uint_as_float(u.y&0xffff0000u);
}
__device__ __forceinline__ void ld_bf4s(const bf16* p, float* o){
  ld_bf4(p, o);
#pragma unroll
  for (int e=0;e<4;e++) o[e] = sanf(o[e]);
}
__device__ __forceinline__ unsigned short f2bfu(float f){
  bf16 h = __float2bfloat16(f);
  return *reinterpret_cast<unsigned short*>(&h);
}
__device__ __forceinline__ uint2 pack_bf4(const float* v){
  uint2 r;
  r.x = (unsigned)f2bfu(v[0]) | ((unsigned)f2bfu(v[1])<<16);
  r.y = (unsigned)f2bfu(v[2]) | ((unsigned)f2bfu(v[3])<<16);
  return r;
}
__device__ __forceinline__ bf16x8 u4_to_b8(uint4 u){
  union { uint4 u; bf16x8 b; } cv; cv.u = u; return cv.b;
}

// ---- fully-unrolled forward substitution (template-const indices: rule #20) ----
template<int I> __device__ __forceinline__ void fsub_step(float* v, const float (*sa)[64]){
  const float* ar = sa[I];
  float s0=0.f,s1=0.f,s2=0.f,s3=0.f;
  constexpr int I4 = I & ~3;
#pragma unroll
  for (int j=0;j<I4;j+=4){
    float4 a4 = *(const float4*)&ar[j];
    s0 += a4.x*v[j+0]; s1 += a4.y*v[j+1]; s2 += a4.z*v[j+2]; s3 += a4.w*v[j+3];
  }
#pragma unroll
  for (int j=I4;j<I;j++) s0 += ar[j]*v[j];
  v[I] += (s0+s2)+(s1+s3);
}
template<int I> __device__ __forceinline__ void fsub_all(float* v, const float (*sa)[64]){
  if constexpr (I >= 1){
    fsub_all<I-1>(v, sa);
    fsub_step<I>(v, sa);
  }
}

// ---------------- fp32 -> bf16 cast ----------------
__global__ __launch_bounds__(256) void cast_f2b(
    const float* __restrict__ src, bf16* __restrict__ dst, int n4)
{
  int i = blockIdx.x*256 + threadIdx.x;
  if (i >= n4) return;
  float4 v = *(const float4*)&src[(size_t)i*4];
  float a[4] = {v.x, v.y, v.z, v.w};
  *(uint2*)&dst[(size_t)i*4] = pack_bf4(a);
}

// ---------------- MFMA GEMM: Y[M,N] = X[M,K](bf16) @ W[N,K](bf16)^T ----------------
// global_load_lds width-16 staging, linear LDS dest, both-sides XOR swizzle.
template<typename OUT_T>
__global__ __launch_bounds__(256) void gemm_bt_mfma(
    const bf16* __restrict__ X, const bf16* __restrict__ W,
    OUT_T* __restrict__ Y, int M, int N, int K)
{
  __shared__ __align__(16) bf16 As[128*64];
  __shared__ __align__(16) bf16 Bs[128*64];
  const int tid = threadIdx.x;
  const int wv = tid >> 6;
  const int lane = tid & 63;
  const int row0 = blockIdx.y*128, col0 = blockIdx.x*128;
  const int mw = (wv&1)*64, nw = (wv>>1)*64;
  const int q = lane >> 4;
  const int l15 = lane & 15;
  const int swr = l15 & 7;
  f32x4 acc[4][4];
#pragma unroll
  for (int mi=0;mi<4;mi++)
#pragma unroll
    for (int ni=0;ni<4;ni++) acc[mi][ni] = (f32x4){0.f,0.f,0.f,0.f};

  const int sr8 = lane >> 3;
  const int scs = ((lane & 7) ^ sr8) * 8;
  for (int k0=0;k0<K;k0+=64){
#pragma unroll
    for (int i=0;i<4;i++){
      __builtin_amdgcn_global_load_lds(
          (const void*)&X[(size_t)(row0 + i*32 + wv*8 + sr8)*K + k0 + scs],
          (void*)&As[i*2048 + wv*512], 16, 0, 0);
      __builtin_amdgcn_global_load_lds(
          (const void*)&W[(size_t)(col0 + i*32 + wv*8 + sr8)*K + k0 + scs],
          (void*)&Bs[i*2048 + wv*512], 16, 0, 0);
    }
    __syncthreads();
#pragma unroll
    for (int ks=0; ks<64; ks+=32){
      bf16x8 af[4], bfr[4];
#pragma unroll
      for (int i=0;i<4;i++){
        const int cc = (((ks>>3) + q) ^ swr) * 8;
        af[i]  = *(const bf16x8*)&As[(mw + i*16 + l15)*64 + cc];
        bfr[i] = *(const bf16x8*)&Bs[(nw + i*16 + l15)*64 + cc];
      }
#pragma unroll
      for (int mi=0;mi<4;mi++)
#pragma unroll
        for (int ni=0;ni<4;ni++)
          acc[mi][ni] = __builtin_amdgcn_mfma_f32_16x16x32_bf16(af[mi], bfr[ni], acc[mi][ni], 0,0,0);
    }
    __syncthreads();
  }
#pragma unroll
  for (int mi=0;mi<4;mi++){
#pragma unroll
    for (int reg=0;reg<4;reg++){
      int row = row0 + mw + mi*16 + q*4 + reg;
#pragma unroll
      for (int ni=0;ni<4;ni++){
        int col = col0 + nw + ni*16 + l15;
        if constexpr (sizeof(OUT_T) == 2)
          Y[(size_t)row*N + col] = (OUT_T)__float2bfloat16(acc[mi][ni][reg]);
        else
          Y[(size_t)row*N + col] = (OUT_T)acc[mi][ni][reg];
      }
    }
  }
}

// ------------- beta = sigmoid(x@Wb^T), decay = -exp(A_log)*softplus(x@Wa^T+dt_bias) -------------
__global__ __launch_bounds__(256) void proj_small(
    const float* __restrict__ x, const float* __restrict__ Wb, const float* __restrict__ Wa,
    const float* __restrict__ dt_bias, const float* __restrict__ A_log,
    float* __restrict__ beta_out, float* __restrict__ dec_out)
{
  const int w = threadIdx.x >> 6;
  const int lane = threadIdx.x & 63;
  const int bt = blockIdx.x*4 + w;
  const int b = bt >> 12, t = bt & (T_-1);
  const float* xr = x + (size_t)bt*D_;
  float xv[16];
#pragma unroll
  for (int p=0;p<4;p++){
    float4 v = *(const float4*)&xr[lane*16 + p*4];
    xv[p*4+0]=v.x; xv[p*4+1]=v.y; xv[p*4+2]=v.z; xv[p*4+3]=v.w;
  }
  float accb[H_], acca[H_];
#pragma unroll
  for (int h=0;h<H_;h++){
    float sb=0.f, sa=0.f;
#pragma unroll
    for (int p=0;p<4;p++){
      float4 wb = *(const float4*)&Wb[(size_t)h*D_ + lane*16 + p*4];
      float4 wa = *(const float4*)&Wa[(size_t)h*D_ + lane*16 + p*4];
      sb += xv[p*4+0]*wb.x + xv[p*4+1]*wb.y + xv[p*4+2]*wb.z + xv[p*4+3]*wb.w;
      sa += xv[p*4+0]*wa.x + xv[p*4+1]*wa.y + xv[p*4+2]*wa.z + xv[p*4+3]*wa.w;
    }
    accb[h]=sb; acca[h]=sa;
  }
#pragma unroll
  for (int h=0;h<H_;h++){
#pragma unroll
    for (int m=1;m<64;m<<=1){
      accb[h] += __shfl_xor(accb[h], m, 64);
      acca[h] += __shfl_xor(acca[h], m, 64);
    }
  }
  if (lane < H_) {
    int h = lane;
    beta_out[(size_t)(b*H_+h)*T_ + t] = 1.f/(1.f+expf(-accb[h]));
  } else if (lane < 2*H_) {
    int h = lane - H_;
    float z = acca[h] + dt_bias[h];
    float sp = fmaxf(z,0.f) + log1pf(expf(-fabsf(z)));
    dec_out[(size_t)(b*H_+h)*T_ + t] = -expf(A_log[h]) * sp;
  }
}

// ------------- xinv + fused fp32->bf16 cast of x -------------
__global__ __launch_bounds__(256) void xinv_kernel(
    const float* __restrict__ x, float* __restrict__ xinv, bf16* __restrict__ xb)
{
  const int bt = blockIdx.x;
  const int b = bt >> 12, t = bt & (T_-1);
  const int tid = threadIdx.x;
  float4 xv = *(const float4*)&x[(size_t)bt*D_ + tid*4];
  float a[4] = {xv.x, xv.y, xv.z, xv.w};
  *(uint2*)&xb[(size_t)bt*D_ + tid*4] = pack_bf4(a);
  float ss = xv.x*xv.x + xv.y*xv.y + xv.z*xv.z + xv.w*xv.w;
#pragma unroll
  for (int m=1;m<32;m<<=1) ss += __shfl_xor(ss, m, 32);
  const int h = tid >> 5;
  if ((tid & 31) == 0)
    xinv[(size_t)(b*H_+h)*T_ + t] = rsqrtf(ss + 1e-6f);
}

// ------------- per-chunk cumsum of decay (fp32) -------------
__global__ __launch_bounds__(256) void cumsum_dec(
    const float* __restrict__ dec_raw, float* __restrict__ dec_cum)
{
  int g = blockIdx.x*4 + (threadIdx.x>>6);
  int lane = threadIdx.x & 63;
  float v = sanf(dec_raw[(size_t)g*C_ + lane]);
#pragma unroll
  for (int off=1; off<64; off<<=1){
    float u = __shfl_up(v, off, 64);
    if (lane >= off) v += u;
  }
  dec_cum[(size_t)g*C_ + lane] = v;
}

// ------------- per-chunk prep, MFMA version -------------
__global__ __launch_bounds__(256) void chunk_prep(
    const bf16* __restrict__ xb, const float* __restrict__ xinv,
    const bf16* __restrict__ vpre, const float* __restrict__ cw, const float* __restrict__ cb,
    const float* __restrict__ beta, const float* __restrict__ dec,
    bf16* __restrict__ vchk, bf16* __restrict__ wkc, bf16* __restrict__ attn)
{
  __shared__ __align__(16) bf16 s_x[65][136];    // s_x[r] = x[t0+r-1] raw bf16
  __shared__ __align__(16) float s_a[64][64];    // A matrix (fp32, strict lower)
  __shared__ float s_dec[64], s_beta[64], s_invsh[64], s_negbi[64], s_rsc[64], s_sc2[64];

  const int tid = threadIdx.x;
  const int chunk = blockIdx.x;
  const int bh = chunk >> 6;
  const int nc = chunk & 63;
  const int b = bh >> 3, h = bh & 7;
  const int t0 = nc * C_;
  const size_t xrow = (size_t)b*T_;
  const size_t rowb = (size_t)bh*T_ + t0;
  const size_t kobase = rowb * K_;
  const int w = tid >> 6;
  const int lane = tid & 63;
  const int l15 = lane & 15;
  const int q = lane >> 4;

  for (int idx = tid; idx < 65*16; idx += 256){
    int r = idx >> 4;
    int seg = (idx & 15) * 8;
    int t = t0 + r - 1;
    int tr = t < 0 ? 0 : t;
    *(uint4*)&s_x[r][seg] = *(const uint4*)&xb[(xrow + tr)*D_ + h*K_ + seg];
  }
  if (tid < C_){
    int c = tid;
    float dv  = sanf(dec[rowb + c]);
    float bet = sanf(beta[rowb + c]);
    float invc = sanf(xinv[rowb + c]);
    int tm1 = t0 + c - 1;
    float ivs = (tm1 >= 0) ? sanf(xinv[(size_t)bh*T_ + tm1]) : 0.f;
    s_dec[c] = dv;
    s_beta[c] = bet;
    s_invsh[c] = ivs;
    s_negbi[c] = -bet * ivs;
    s_rsc[c] = invc * 0.08838834764831845f;
    s_sc2[c] = ivs * bet * expn(dv);
  }
  __syncthreads();

  bf16x8 aG[4], aT[4];
#pragma unroll
  for (int ks=0; ks<4; ks++){
    aG[ks] = *(const bf16x8*)&s_x[16*w + l15][ks*32 + q*8];
    aT[ks] = *(const bf16x8*)&s_x[16*w + l15 + 1][ks*32 + q*8];
  }
  f32x4 accG[4], accT[4];
#pragma unroll
  for (int J=0;J<4;J++){ accG[J]=(f32x4){0.f,0.f,0.f,0.f}; accT[J]=(f32x4){0.f,0.f,0.f,0.f}; }
#pragma unroll
  for (int J=0;J<4;J++){
    if (J <= w){
#pragma unroll
      for (int ks=0; ks<4; ks++){
        bf16x8 bfrag = *(const bf16x8*)&s_x[16*J + l15][ks*32 + q*8];
        accG[J] = __builtin_amdgcn_mfma_f32_16x16x32_bf16(aG[ks], bfrag, accG[J], 0,0,0);
        accT[J] = __builtin_amdgcn_mfma_f32_16x16x32_bf16(aT[ks], bfrag, accT[J], 0,0,0);
      }
    }
  }
  {
    const int i0 = 16*w + q*4;
#pragma unroll
    for (int J=0;J<4;J++){
      const int j = 16*J + l15;
#pragma unroll
      for (int reg=0;reg<4;reg++){
        const int i = i0 + reg;
        if (j < i)
          s_a[i][j] = s_negbi[i] * s_invsh[j] * expn(s_dec[i]-s_dec[j]) * accG[J][reg];
        float val = 0.f;
        if (j <= i)
          val = s_rsc[i] * s_invsh[j] * expn(s_dec[i]-s_dec[j]) * accT[J][reg];
        attn[(size_t)chunk*4096 + i*64 + j] = __float2bfloat16(val);
      }
    }
  }

  float v[64];
  if (tid < 128){
    const int col = tid;
    float4 cwv = *(const float4*)&cw[(h*K_+col)*4];
    const float cbv = cb[h*K_+col];
    const bf16* vp = vpre + (xrow + t0)*D_ + h*K_ + col;
    float win0, win1, win2;
    { int t = t0-3; win0 = (t>=0)? sanf(__bfloat162float(vpre[(xrow+t)*D_+h*K_+col])) : 0.f; }
    { int t = t0-2; win1 = (t>=0)? sanf(__bfloat162float(vpre[(xrow+t)*D_+h*K_+col])) : 0.f; }
    { int t = t0-1; win2 = (t>=0)? sanf(__bfloat162float(vpre[(xrow+t)*D_+h*K_+col])) : 0.f; }
#pragma unroll
    for (int c8=0; c8<8; c8++){
      float nv[8];
#pragma unroll
      for (int u=0;u<8;u++) nv[u] = sanf(__bfloat162float(vp[(size_t)(c8*8+u)*D_]));
#pragma unroll
      for (int u=0;u<8;u++){
        const int c = c8*8+u;
        float a = cbv + cwv.x*win0 + cwv.y*win1 + cwv.z*win2 + cwv.w*nv[u];
        v[c] = siluf(a) * s_beta[c];
        win0=win1; win1=win2; win2=nv[u];
      }
    }
  } else {
    const int col = tid - 128;
#pragma unroll
    for (int c=0;c<64;c++)
      v[c] = __bfloat162float(s_x[c][col]) * s_sc2[c];
  }
  __syncthreads();   // s_a complete

  fsub_all<63>(v, s_a);

  {
    const int col = tid & 127;
    bf16* dst = (tid < 128 ? vchk : wkc) + kobase + col;
#pragma unroll
    for (int c=0;c<64;c++)
      dst[(size_t)c*K_] = __float2bfloat16(v[c]);
  }
}

// ------------- scan body: LDS-diet + 8-wave role split (verified R10) -------------
__device__ __forceinline__ void scan_body(
    int sid, int tid, unsigned char* smem,
    const bf16* __restrict__ xb, const float* __restrict__ xinv, bf16* vo,
    const bf16* __restrict__ wkc, const bf16* __restrict__ attn,
    const float* __restrict__ dec)
{
  typedef bf16 (*xst_t)[128][72];
  xst_t xst = (xst_t)smem;                        // [2][128][72]
  bf16 (*st_hi)[136] = (bf16(*)[136])(smem + 36864);
  bf16 (*st_lo)[136] = (bf16(*)[136])(smem + 41216);
  bf16 (*vn_t )[72]  = (bf16(*)[72]) (smem + 45568);
  bf16 (*vn_sh)[72]  = (bf16(*)[72]) (smem + 47872);
  bf16 (*vn_sl)[72]  = (bf16(*)[72]) (smem + 50176);

  const int bh = sid & 31;
  const int g  = sid >> 5;
  const int b = bh >> 3, h = bh & 7;
  const int j0 = g*16;
  const int w  = tid >> 6;
  const int wm = w & 3;
  const int lane = tid & 63;
  const int l15 = lane & 15;
  const int q = lane >> 4;
  const int wrow = 16*wm;
  const int c0 = wrow + q*4;
  const size_t xrow = (size_t)b*T_;
  const size_t bhT = (size_t)bh*T_;

  for (int e=tid; e<16*136; e+=512){
    ((unsigned short*)&st_hi[0][0])[e] = 0;
    ((unsigned short*)&st_lo[0][0])[e] = 0;
  }

  if (w < 4){
    // ========= STATE WAVES =========
    f32x4 accS[2];
    accS[0] = (f32x4){0.f,0.f,0.f,0.f};
    accS[1] = (f32x4){0.f,0.f,0.f,0.f};

    const bf16*  pw   = wkc + (bhT + wrow + l15)*K_ + q*8;
    const bf16*  pv   = vo  + (bhT + c0)*K_ + j0 + l15;
    const float* pd   = dec + bhT + c0;
    const float* pd63 = dec + bhT + 63;
    const float* pxm  = xinv + bhT + c0;

    uint4 P_w[4]; bf16 P_v[4]; float4 P_d; float P_d63, P_xm[4];
#pragma unroll
    for (int ks=0; ks<4; ks++) P_w[ks] = *(const uint4*)(pw + ks*32);
#pragma unroll
    for (int r=0;r<4;r++) P_v[r] = pv[(size_t)r*K_];
    P_d = *(const float4*)pd;
    P_d63 = *pd63;
#pragma unroll
    for (int r=0;r<4;r++){
      int tm1 = c0 + r - 1;
      P_xm[r] = (tm1 >= 0) ? xinv[bhT + tm1] : 0.f;
    }
    BAR_LGKM();

    for (int nc=0; nc<N_CH; nc++){
      float d63s = sanf(P_d63);
      float a63 = expn(d63s);
      float cd[4] = {sanf(P_d.x), sanf(P_d.y), sanf(P_d.z), sanf(P_d.w)};
      float scv[4], vinitf[4];
#pragma unroll
      for (int r=0;r<4;r++){
        scv[r] = sanf(P_xm[r]) * expn(d63s - cd[r]);
        vinitf[r] = __bfloat162float(P_v[r]);
      }

      f32x4 accV;
#pragma unroll
      for (int r=0;r<4;r++) accV[r] = vinitf[r];
      __builtin_amdgcn_s_setprio(1);
#pragma unroll
      for (int ks=0; ks<4; ks++){
        bf16x8 bh_ = *(const bf16x8*)&st_hi[l15][ks*32 + q*8];
        bf16x8 bl_ = *(const bf16x8*)&st_lo[l15][ks*32 + q*8];
        uint4 uw = P_w[ks];
        uw.x ^= 0x80008000u; uw.y ^= 0x80008000u; uw.z ^= 0x80008000u; uw.w ^= 0x80008000u;
        bf16x8 a1 = u4_to_b8(uw);
        accV = __builtin_amdgcn_mfma_f32_16x16x32_bf16(a1, bh_, accV, 0,0,0);
        accV = __builtin_amdgcn_mfma_f32_16x16x32_bf16(a1, bl_, accV, 0,0,0);
      }
      __builtin_amdgcn_s_setprio(0);
      {
        float v4[4] = {accV[0],accV[1],accV[2],accV[3]};
        *(uint2*)&vn_t[l15][c0] = pack_bf4(v4);
        float vs[4];
#pragma unroll
        for (int r=0;r<4;r++) vs[r] = accV[r] * scv[r];
        uint2 ph = pack_bf4(vs);
        float lo4[4];
        lo4[0] = vs[0] - __uint_as_float(ph.x << 16);
        lo4[1] = vs[1] - __uint_as_float(ph.x & 0xffff0000u);
        lo4[2] = vs[2] - __uint_as_float(ph.y << 16);
        lo4[3] = vs[3] - __uint_as_float(ph.y & 0xffff0000u);
        *(uint2*)&vn_sh[l15][c0] = ph;
        *(uint2*)&vn_sl[l15][c0] = pack_bf4(lo4);
      }
      if (nc+1 < N_CH){ pw += (size_t)C_*K_; pv += (size_t)C_*K_; pd += C_; pd63 += C_; pxm += C_; }
#pragma unroll
      for (int ks=0; ks<4; ks++) P_w[ks] = *(const uint4*)(pw + ks*32);
#pragma unroll
      for (int r=0;r<4;r++) P_v[r] = pv[(size_t)r*K_];
      P_d = *(const float4*)pd;
      P_d63 = *pd63;
#pragma unroll
      for (int r=0;r<4;r++) P_xm[r] = pxm[r-1];
      BAR_LGKM();   // b2: vn ready

      __builtin_amdgcn_s_setprio(1);
      bf16x8 aH[2], aL[2];
#pragma unroll
      for (int ks=0; ks<2; ks++){
        aH[ks] = *(const bf16x8*)&vn_sh[l15][ks*32 + q*8];
        aL[ks] = *(const bf16x8*)&vn_sl[l15][ks*32 + q*8];
      }
#pragma unroll
      for (int sub=0; sub<2; sub++){
        f32x4 acc = accS[sub];
#pragma unroll
        for (int r=0;r<4;r++) acc[r] *= a63;
#pragma unroll
        for (int ks=0; ks<2; ks++){
          bf16x8 bX = *(const bf16x8*)&xst[nc&1][32*wm + 16*sub + l15][ks*32 + q*8];
          acc = __builtin_amdgcn_mfma_f32_16x16x32_bf16(aH[ks], bX, acc, 0,0,0);
          acc = __builtin_amdgcn_mfma_f32_16x16x32_bf16(aL[ks], bX, acc, 0,0,0);
        }
        accS[sub] = acc;
#pragma unroll
        for (int r=0;r<4;r++){
          float sv = acc[r];
          bf16 hb = __float2bfloat16(sv);
          st_hi[q*4+r][32*wm + 16*sub + l15] = hb;
          st_lo[q*4+r][32*wm + 16*sub + l15] = __float2bfloat16(sv - __bfloat162float(hb));
        }
      }
      __builtin_amdgcn_s_setprio(0);
      BAR_LGKM();   // b3
    }
  } else {
    // ========= OUTPUT WAVES =========
    const int tp = tid - 256;
    const int xc0 = (tp & 31)*2;
    const int xkb = (tp >> 5)*16;

    uint4 T_r[4];
    uint4 P_x[4], P_a[2];
    float4 P_dP, P_xi;

    {
      int t1 = xc0 - 1;
      const bf16* p1 = xb + (xrow + (t1<0?0:t1))*D_ + h*K_ + xkb;
      const bf16* p2 = xb + (xrow + xc0)*D_ + h*K_ + xkb;
      T_r[0]=*(const uint4*)p1; T_r[1]=*(const uint4*)(p1+8);
      T_r[2]=*(const uint4*)p2; T_r[3]=*(const uint4*)(p2+8);
    }
    {
      unsigned r1[8]={T_r[0].x,T_r[0].y,T_r[0].z,T_r[0].w,T_r[1].x,T_r[1].y,T_r[1].z,T_r[1].w};
      unsigned r2[8]={T_r[2].x,T_r[2].y,T_r[2].z,T_r[2].w,T_r[3].x,T_r[3].y,T_r[3].z,T_r[3].w};
#pragma unroll
      for (int i2=0;i2<8;i2++){
        *(unsigned*)&xst[0][xkb + 2*i2][xc0]     = (r1[i2] & 0xffffu) | (r2[i2] << 16);
        *(unsigned*)&xst[0][xkb + 2*i2 + 1][xc0] = (r1[i2] >> 16) | (r2[i2] & 0xffff0000u);
      }
    }
    {
      const bf16* p1 = xb + (xrow + C_ + xc0 - 1)*D_ + h*K_ + xkb;
      const bf16* p2 = xb + (xrow + C_ + xc0)*D_ + h*K_ + xkb;
      T_r[0]=*(const uint4*)p1; T_r[1]=*(const uint4*)(p1+8);
      T_r[2]=*(const uint4*)p2; T_r[3]=*(const uint4*)(p2+8);
    }
    const bf16* pt1 = xb + (xrow + 2*C_ + xc0 - 1)*D_ + h*K_ + xkb;
    const bf16* pt2 = xb + (xrow + 2*C_ + xc0)*D_ + h*K_ + xkb;

    const bf16*  px  = xb + (xrow + wrow + l15)*D_ + h*K_ + q*8;
    const bf16*  pa  = attn + (size_t)(bh*N_CH)*4096 + (wrow + l15)*64 + q*8;
    const float* pdP = dec + bhT + c0;
    const float* pxi = xinv + bhT + c0;
    bf16*        pvo = vo + (bhT + c0)*K_ + j0 + l15;

#pragma unroll
    for (int ks=0; ks<4; ks++) P_x[ks] = *(const uint4*)(px + ks*32);
    P_a[0] = *(const uint4*)pa; P_a[1] = *(const uint4*)(pa + 32);
    P_dP = *(const float4*)pdP;
    P_xi = *(const float4*)pxi;
    BAR_LGKM();

    for (int nc=0; nc<N_CH; nc++){
      float cd[4]  = {sanf(P_dP.x), sanf(P_dP.y), sanf(P_dP.z), sanf(P_dP.w)};
      float cxi[4] = {sanf(P_xi.x), sanf(P_xi.y), sanf(P_xi.z), sanf(P_xi.w)};
      float sov[4];
#pragma unroll
      for (int r=0;r<4;r++) sov[r] = cxi[r] * 0.08838834764831845f * expn(cd[r]);

      {
        unsigned r1[8]={T_r[0].x,T_r[0].y,T_r[0].z,T_r[0].w,T_r[1].x,T_r[1].y,T_r[1].z,T_r[1].w};
        unsigned r2[8]={T_r[2].x,T_r[2].y,T_r[2].z,T_r[2].w,T_r[3].x,T_r[3].y,T_r[3].z,T_r[3].w};
        const int buf = (nc+1)&1;
#pragma unroll
        for (int i2=0;i2<8;i2++){
          *(unsigned*)&xst[buf][xkb + 2*i2][xc0]     = (r1[i2] & 0xffffu) | (r2[i2] << 16);
          *(unsigned*)&xst[buf][xkb + 2*i2 + 1][xc0] = (r1[i2] >> 16) | (r2[i2] & 0xffff0000u);
        }
      }
      if (nc+2 < N_CH){
        T_r[0]=*(const uint4*)pt1; T_r[1]=*(const uint4*)(pt1+8);
        T_r[2]=*(const uint4*)pt2; T_r[3]=*(const uint4*)(pt2+8);
        pt1 += (size_t)C_*D_; pt2 += (size_t)C_*D_;
      }

      f32x4 accP = (f32x4){0.f,0.f,0.f,0.f};
      __builtin_amdgcn_s_setprio(1);
#pragma unroll
      for (int ks=0; ks<4; ks++){
        bf16x8 bh_ = *(const bf16x8*)&st_hi[l15][ks*32 + q*8];
        bf16x8 bl_ = *(const bf16x8*)&st_lo[l15][ks*32 + q*8];
        bf16x8 a2 = u4_to_b8(P_x[ks]);
        accP = __builtin_amdgcn_mfma_f32_16x16x32_bf16(a2, bh_, accP, 0,0,0);
        accP = __builtin_amdgcn_mfma_f32_16x16x32_bf16(a2, bl_, accP, 0,0,0);
      }
      __builtin_amdgcn_s_setprio(0);
      f32x4 oacc;
#pragma unroll
      for (int r=0;r<4;r++) oacc[r] = accP[r] * sov[r];
      if (nc+1 < N_CH){ px += (size_t)C_*D_; pdP += C_; pxi += C_; }
#pragma unroll
      for (int ks=0; ks<4; ks++) P_x[ks] = *(const uint4*)(px + ks*32);
      P_dP = *(const float4*)pdP;
      P_xi = *(const float4*)pxi;
      BAR_LGKM();   // b2: vn_t ready

      __builtin_amdgcn_s_setprio(1);
#pragma unroll
      for (int ks=0; ks<2; ks++){
        bf16x8 bV = *(const bf16x8*)&vn_t[l15][ks*32 + q*8];
        bf16x8 aA = u4_to_b8(P_a[ks]);
        oacc = __builtin_amdgcn_mfma_f32_16x16x32_bf16(aA, bV, oacc, 0,0,0);
      }
      __builtin_amdgcn_s_setprio(0);
#pragma unroll
      for (int r=0;r<4;r++) pvo[(size_t)r*K_] = __float2bfloat16(oacc[r]);
      pvo += (size_t)C_*K_;
      if (nc+1 < N_CH){ pa += 4096; }
      P_a[0] = *(const uint4*)pa; P_a[1] = *(const uint4*)(pa + 32);
      BAR_LGKM();   // b3
    }
  }
}

// ------------- 512-thread 256x128 GEMM tile (gate = xb @ Wgb^T) -------------
// Same verified gload_lds + both-sides-XOR structure; As 256x64 (32KB), Bs
// 128x64 (16KB) -> 48KB <= scan's 52.5KB.
__device__ __forceinline__ void gemm256_body(
    const bf16* __restrict__ X, const bf16* __restrict__ W,
    bf16* __restrict__ Y, int gid, int tid, bf16* As, bf16* Bs)
{
  const int wv = tid >> 6;            // 0..7
  const int lane = tid & 63;
  const int bx = gid & 7, by = gid >> 3;   // bx 0..7, by 0..63
  const int row0 = by*256, col0 = bx*128;
  const int mw = (wv&3)*64, nw = (wv>>2)*64;
  const int q = lane >> 4;
  const int l15 = lane & 15;
  const int swr = l15 & 7;
  f32x4 acc[4][4];
#pragma unroll
  for (int mi=0;mi<4;mi++)
#pragma unroll
    for (int ni=0;ni<4;ni++) acc[mi][ni] = (f32x4){0.f,0.f,0.f,0.f};

  const int sr8 = lane >> 3;
  const int scs = ((lane & 7) ^ sr8) * 8;
  for (int k0=0;k0<D_;k0+=64){
#pragma unroll
    for (int j=0;j<4;j++){
      __builtin_amdgcn_global_load_lds(
          (const void*)&X[(size_t)(row0 + (wv*4+j)*8 + sr8)*D_ + k0 + scs],
          (void*)&As[(wv*4+j)*512], 16, 0, 0);
    }
#pragma unroll
    for (int j=0;j<2;j++){
      __builtin_amdgcn_global_load_lds(
          (const void*)&W[(size_t)(col0 + (wv*2+j)*8 + sr8)*D_ + k0 + scs],
          (void*)&Bs[(wv*2+j)*512], 16, 0, 0);
    }
    __syncthreads();
#pragma unroll
    for (int ks=0; ks<64; ks+=32){
      bf16x8 af[4], bfr[4];
#pragma unroll
      for (int i=0;i<4;i++){
        const int cc = (((ks>>3) + q) ^ swr) * 8;
        af[i]  = *(const bf16x8*)&As[(mw + i*16 + l15)*64 + cc];
        bfr[i] = *(const bf16x8*)&Bs[(nw + i*16 + l15)*64 + cc];
      }
#pragma unroll
      for (int mi=0;mi<4;mi++)
#pragma unroll
        for (int ni=0;ni<4;ni++)
          acc[mi][ni] = __builtin_amdgcn_mfma_f32_16x16x32_bf16(af[mi], bfr[ni], acc[mi][ni], 0,0,0);
    }
    __syncthreads();
  }
#pragma unroll
  for (int mi=0;mi<4;mi++){
#pragma unroll
    for (int reg=0;reg<4;reg++){
      int row = row0 + mw + mi*16 + q*4 + reg;
#pragma unroll
      for (int ni=0;ni<4;ni++){
        int col = col0 + nw + ni*16 + l15;
        Y[(size_t)row*D_ + col] = __float2bfloat16(acc[mi][ni][reg]);
      }
    }
  }
}

// ------------- fused: scan (blocks 0-255, one per CU) + gate GEMM (256-767) -------------
// Scan blocks FIRST in dispatch order -> all start at t=0, one per CU
// (bid%256 unique), and bid%8 == bh%8 preserves the XCD sibling locality that
// standalone scan measured (58 MB fetch). R8 failed on both counts.
__global__ __launch_bounds__(512, 4) void scan_gate_kernel(
    const bf16* __restrict__ xb, const float* __restrict__ xinv, bf16* vo,
    const bf16* __restrict__ wkc, const bf16* __restrict__ attn,
    const float* __restrict__ dec,
    const bf16* __restrict__ Wgb, bf16* __restrict__ gate)
{
  __shared__ __align__(16) unsigned char smem[52480];
  const int bid = blockIdx.x;
  if (bid < 256){
    scan_body(bid, threadIdx.x, smem, xb, xinv, vo, wkc, attn, dec);
  } else {
    gemm256_body(xb, Wgb, gate, bid - 256, threadIdx.x,
                 (bf16*)smem, (bf16*)(smem + 32768));
  }
}

// ------------- per-head RMSNorm * norm_w * silu(gate); gate buffer overwritten in place -------------
__global__ __launch_bounds__(256) void norm_gate(
    const bf16* __restrict__ o, bf16* gio, const float* __restrict__ norm_w)
{
  const int bt = blockIdx.x;
  const int b = bt >> 12, t = bt & (T_-1);
  const int tid = threadIdx.x;
  const int h = tid >> 5;
  const int kk = (tid & 31)*4;
  float ov[4];
  ld_bf4s(o + ((size_t)(b*H_+h)*T_ + t)*K_ + kk, ov);
  float ss = ov[0]*ov[0] + ov[1]*ov[1] + ov[2]*ov[2] + ov[3]*ov[3];
#pragma unroll
  for (int m=1;m<32;m<<=1) ss += __shfl_xor(ss, m, 32);
  float r = rsqrtf(ss*(1.f/128.f) + 1e-5f);
  float4 nw = *(const float4*)&norm_w[kk];
  float gv[4];
  ld_bf4s(gio + (size_t)bt*D_ + tid*4, gv);
  float res[4];
  res[0] = ov[0]*r*nw.x * siluf(gv[0]);
  res[1] = ov[1]*r*nw.y * siluf(gv[1]);
  res[2] = ov[2]*r*nw.z * siluf(gv[2]);
  res[3] = ov[3]*r*nw.w * siluf(gv[3]);
  *(uint2*)&gio[(size_t)bt*D_ + tid*4] = pack_bf4(res);
}

extern "C" void kernel_launch(void* const* d_in, const int* in_sizes, int n_in,
                              void* d_out, int out_size, void* d_ws, size_t ws_size,
                              hipStream_t stream)
{
  const float* x       = (const float*)d_in[0];
  const float* Wv      = (const float*)d_in[1];
  const float* Wg      = (const float*)d_in[2];
  const float* Wo      = (const float*)d_in[3];
  const float* Wb      = (const float*)d_in[4];
  const float* Wa      = (const float*)d_in[5];
  const float* dt_bias = (const float*)d_in[6];
  const float* A_log   = (const float*)d_in[7];
  const float* norm_w  = (const float*)d_in[8];
  const float* conv_w  = (const float*)d_in[9];
  const float* conv_b  = (const float*)d_in[10];
  float* out = (float*)d_out;

  const size_t BTD = (size_t)B_*T_*D_;
  const size_t BHT = (size_t)B_*H_*T_;
  const size_t DD  = (size_t)D_*D_;

  // ws layout (~108.6 MB): fp32 smalls, bf16 weight copies, then big bf16 buffers
  float* beta = (float*)d_ws;          // 0.5 MiB each
  float* decr = beta + BHT;
  float* decc = decr + BHT;
  float* xinv = decc + BHT;
  bf16* Wvb = (bf16*)(xinv + BHT);     // 2 MiB each
  bf16* Wgb = Wvb + DD;
  bf16* Wob = Wgb + DD;
  bf16* xb   = Wob + DD;               // 33.5 MiB: bf16 copy of x
  bf16* vpre = xb + BTD;               // 33.5 MiB: Wv-GEMM out; later gate/og
  bf16* wkc  = vpre + BTD;             // 33.5 MiB
  // d_out (67 MB fp32) hosts: [vchk->o bf16: BTD][attn bf16: BTD/2]
  bf16* vo   = (bf16*)d_out;
  bf16* attn = vo + BTD;

  dim3 gemm_grid(D_/128, BT_/128);   // (8, 128)
  xinv_kernel<<<BT_, 256, 0, stream>>>(x, xinv, xb);   // fused fp32->bf16 cast of x
  cast_f2b<<<(DD/4+255)/256, 256, 0, stream>>>(Wv, Wvb, DD/4);
  cast_f2b<<<(DD/4+255)/256, 256, 0, stream>>>(Wg, Wgb, DD/4);
  cast_f2b<<<(DD/4+255)/256, 256, 0, stream>>>(Wo, Wob, DD/4);
  gemm_bt_mfma<bf16><<<gemm_grid, 256, 0, stream>>>(xb, Wvb, vpre, BT_, D_, D_);
  proj_small<<<BT_/4, 256, 0, stream>>>(x, Wb, Wa, dt_bias, A_log, beta, decr);
  cumsum_dec<<<(BHT/C_)/4, 256, 0, stream>>>(decr, decc);
  chunk_prep<<<B_*H_*N_CH, 256, 0, stream>>>(xb, xinv, vpre, conv_w, conv_b,
                                             beta, decc, vo /*vchk*/, wkc, attn);
  // fused: scan (256 blocks, first in dispatch order -> one per CU at t=0)
  // + independent gate GEMM (512 blocks of 256x128 tiles) filling idle waves.
  scan_gate_kernel<<<768, 512, 0, stream>>>(xb, xinv, vo, wkc, attn, decc,
                                            Wgb, vpre /*gate*/);
  norm_gate<<<BT_, 256, 0, stream>>>(vo /*o*/, vpre /*gate->og*/, norm_w);
  gemm_bt_mfma<float><<<gemm_grid, 256, 0, stream>>>(vpre, Wob, out, BT_, D_, D_);
}